// Round 1
// baseline (1482.218 us; speedup 1.0000x reference)
//
#include <hip/hip_runtime.h>
#include <math.h>

// Problem constants
#define DD 768
#define SS 1024
#define BB 2
#define HH 12
#define DH 64
#define NW 65
#define HALFW 32

// ---------------- LayerNorm: one block per row ----------------
__global__ void ln_kernel(const float* __restrict__ x, const float* __restrict__ gamma,
                          const float* __restrict__ beta, float* __restrict__ xn) {
    int row = blockIdx.x;                    // 2048 rows
    const float* xr = x + (size_t)row * DD;
    float* outr = xn + (size_t)row * DD;
    int tid = threadIdx.x;                   // 256 threads
    float v[3];
    float s = 0.f, s2 = 0.f;
    #pragma unroll
    for (int r = 0; r < 3; ++r) {
        v[r] = xr[tid + r * 256];
        s += v[r];
        s2 += v[r] * v[r];
    }
    // wave(64) reduce
    #pragma unroll
    for (int o = 32; o > 0; o >>= 1) {
        s  += __shfl_down(s, o);
        s2 += __shfl_down(s2, o);
    }
    __shared__ float ws1[4], ws2[4];
    int wid = tid >> 6, lane = tid & 63;
    if (lane == 0) { ws1[wid] = s; ws2[wid] = s2; }
    __syncthreads();
    __shared__ float mstat[2];
    if (tid == 0) {
        float a = 0.f, b2 = 0.f;
        #pragma unroll
        for (int i = 0; i < 4; ++i) { a += ws1[i]; b2 += ws2[i]; }
        float mean = a / (float)DD;
        float var = b2 / (float)DD - mean * mean;
        mstat[0] = mean;
        mstat[1] = rsqrtf(var + 1e-5f);
    }
    __syncthreads();
    float mean = mstat[0], rstd = mstat[1];
    #pragma unroll
    for (int r = 0; r < 3; ++r) {
        int i = tid + r * 256;
        outr[i] = (v[r] - mean) * rstd * gamma[i] + beta[i];
    }
}

// ---------------- Generic tiled fp32 GEMM ----------------
// C[z][M,N] (+)= act( A[z] @ B[z] + bias ), with optional row-divide and add-source.
// A element (m,k) at A + z*bA + m*sa_m + k*sa_k ; B row-major with row stride N.
// act: 0=none, 1=elu+1, 2=relu, 3=sigmoid
__global__ void gemm_f32(const float* __restrict__ A, const float* __restrict__ Bm,
                         const float* __restrict__ bias, const float* __restrict__ rowdiv,
                         const float* __restrict__ addsrc, float* __restrict__ C,
                         int M, int N, int K, int sa_m, int sa_k,
                         long long bA, long long bB, long long bC,
                         int act, int accum) {
    __shared__ float As[16][65];
    __shared__ float Bs[16][65];
    const float* Ab = A + (long long)blockIdx.z * bA;
    const float* Bb = Bm + (long long)blockIdx.z * bB;
    float* Cb = C + (long long)blockIdx.z * bC;
    int tid = threadIdx.x;
    int tx = tid & 15, ty = tid >> 4;
    int m0 = blockIdx.y * 64, n0 = blockIdx.x * 64;
    float acc[4][4] = {};
    for (int k0 = 0; k0 < K; k0 += 16) {
        if (sa_k == 1) {
            int m = tid >> 2;
            int kk = (tid & 3) * 4;
            const float* ap = Ab + (size_t)(m0 + m) * sa_m + (k0 + kk);
            #pragma unroll
            for (int j = 0; j < 4; ++j) As[kk + j][m] = ap[j];
        } else {
            #pragma unroll
            for (int r = 0; r < 4; ++r) {
                int e = tid + r * 256;
                int m = e & 63;
                int kk = e >> 6;
                As[kk][m] = Ab[(size_t)(m0 + m) * sa_m + (size_t)(k0 + kk) * sa_k];
            }
        }
        #pragma unroll
        for (int r = 0; r < 4; ++r) {
            int e = tid + r * 256;
            int n = e & 63;
            int kk = e >> 6;
            Bs[kk][n] = Bb[(size_t)(k0 + kk) * N + n0 + n];
        }
        __syncthreads();
        #pragma unroll
        for (int kk = 0; kk < 16; ++kk) {
            float a[4], b[4];
            #pragma unroll
            for (int i = 0; i < 4; ++i) a[i] = As[kk][ty * 4 + i];
            #pragma unroll
            for (int j = 0; j < 4; ++j) b[j] = Bs[kk][tx * 4 + j];
            #pragma unroll
            for (int i = 0; i < 4; ++i)
                #pragma unroll
                for (int j = 0; j < 4; ++j)
                    acc[i][j] += a[i] * b[j];
        }
        __syncthreads();
    }
    #pragma unroll
    for (int i = 0; i < 4; ++i) {
        int m = m0 + ty * 4 + i;
        float rd = 1.f;
        if (rowdiv) rd = 1.f / (rowdiv[blockIdx.z * M + m] + 1e-6f);
        #pragma unroll
        for (int j = 0; j < 4; ++j) {
            int n = n0 + tx * 4 + j;
            float v = acc[i][j];
            if (accum) v += Cb[(size_t)m * N + n];
            if (bias) v += bias[n];
            if (rowdiv) v *= rd;
            if (act == 1) v = (v > 0.f) ? (v + 1.f) : expf(v);   // elu(v)+1
            else if (act == 2) v = fmaxf(v, 0.f);
            else if (act == 3) v = 1.f / (1.f + expf(-v));
            if (addsrc) v += addsrc[(size_t)m * N + n];
            Cb[(size_t)m * N + n] = v;
        }
    }
}

// ---------------- kf column sums: kfsum[b,d] = sum_s kf[b,s,d] ----------------
__global__ void kfsum_kernel(const float* __restrict__ kf, float* __restrict__ kfsum) {
    int b = blockIdx.x / 3;
    int d = (blockIdx.x % 3) * 256 + threadIdx.x;
    const float* p = kf + (size_t)b * SS * DD + d;
    float s = 0.f;
    for (int i = 0; i < SS; ++i) s += p[(size_t)i * DD];
    kfsum[b * DD + d] = s;
}

// ---------------- normalizer[b,s] = dot(qf[b,s,:], kfsum[b,:]) ----------------
__global__ void norm_kernel(const float* __restrict__ qf, const float* __restrict__ kfsum,
                            float* __restrict__ nrm) {
    int row = blockIdx.x;                    // 2048
    int b = row / SS;
    const float* q = qf + (size_t)row * DD;
    const float* ks = kfsum + b * DD;
    int tid = threadIdx.x;
    float s = 0.f;
    for (int i = tid; i < DD; i += 256) s += q[i] * ks[i];
    #pragma unroll
    for (int o = 32; o > 0; o >>= 1) s += __shfl_down(s, o);
    __shared__ float wsum[4];
    int wid = tid >> 6, lane = tid & 63;
    if (lane == 0) wsum[wid] = s;
    __syncthreads();
    if (tid == 0) nrm[row] = wsum[0] + wsum[1] + wsum[2] + wsum[3];
}

// ---------------- windowed attention probabilities ----------------
// one thread per (b,s,h); two-pass softmax over 65 window positions
__global__ void attn_score_kernel(const float* __restrict__ qo, const float* __restrict__ ko,
                                  float* __restrict__ attnw) {
    int t = blockIdx.x * blockDim.x + threadIdx.x;
    if (t >= BB * SS * HH) return;
    int h = t % HH;
    int s = (t / HH) % SS;
    int b = t / (HH * SS);
    const float* q = qo + ((size_t)(b * SS + s) * DD) + h * DH;
    float qr[DH];
    #pragma unroll
    for (int d = 0; d < DH; ++d) qr[d] = q[d];
    float mx = -1e30f;
    for (int w = 0; w < NW; ++w) {
        int idx = s - HALFW + w;
        if (idx < 0 || idx >= SS) continue;
        const float* k = ko + ((size_t)(b * SS + idx) * DD) + h * DH;
        float sc = 0.f;
        #pragma unroll
        for (int d = 0; d < DH; ++d) sc += qr[d] * k[d];
        sc *= 0.125f;
        mx = fmaxf(mx, sc);
    }
    float denom = 0.f;
    float* aw = attnw + (size_t)t * NW;
    for (int w = 0; w < NW; ++w) {
        int idx = s - HALFW + w;
        float e = 0.f;
        if (idx >= 0 && idx < SS) {
            const float* k = ko + ((size_t)(b * SS + idx) * DD) + h * DH;
            float sc = 0.f;
            #pragma unroll
            for (int d = 0; d < DH; ++d) sc += qr[d] * k[d];
            sc *= 0.125f;
            e = expf(sc - mx);
            denom += e;
        }
        aw[w] = e;
    }
    float inv = 1.f / denom;
    for (int w = 0; w < NW; ++w) aw[w] *= inv;
}

// ---------------- win_out[b,s,h,d] = sum_w attn*v ----------------
__global__ void win_out_kernel(const float* __restrict__ attnw, const float* __restrict__ vo,
                               float* __restrict__ win) {
    size_t g = (size_t)blockIdx.x * blockDim.x + threadIdx.x;  // B*S*D threads
    int d = (int)(g & 63);
    size_t rest = g >> 6;                     // (b*S+s)*H + h
    int h = (int)(rest % HH);
    size_t bs = rest / HH;                    // b*S + s
    int s = (int)(bs % SS);
    int b = (int)(bs / SS);
    const float* aw = attnw + rest * NW;
    float acc = 0.f;
    for (int w = 0; w < NW; ++w) {
        int idx = s - HALFW + w;
        if (idx < 0 || idx >= SS) continue;
        acc += aw[w] * vo[((size_t)(b * SS + idx) * DD) + h * DH + d];
    }
    win[g] = acc;
}

// ---------------- fused = gate*lin + (1-gate)*win ----------------
__global__ void fuse_kernel(const float* __restrict__ gate, const float* __restrict__ lin,
                            const float* __restrict__ win, float* __restrict__ fused) {
    size_t g = (size_t)blockIdx.x * blockDim.x + threadIdx.x;
    float gt = gate[g];
    fused[g] = gt * lin[g] + (1.f - gt) * win[g];
}

extern "C" void kernel_launch(void* const* d_in, const int* in_sizes, int n_in,
                              void* d_out, int out_size, void* d_ws, size_t ws_size,
                              hipStream_t stream) {
    const float* x      = (const float*)d_in[0];
    const float* W_q    = (const float*)d_in[1];
    const float* b_q    = (const float*)d_in[2];
    const float* W_k    = (const float*)d_in[3];
    const float* b_k    = (const float*)d_in[4];
    const float* W_v    = (const float*)d_in[5];
    const float* b_v    = (const float*)d_in[6];
    const float* W_ql   = (const float*)d_in[7];
    const float* b_ql   = (const float*)d_in[8];
    const float* W_kl   = (const float*)d_in[9];
    const float* b_kl   = (const float*)d_in[10];
    const float* W_vl   = (const float*)d_in[11];
    const float* b_vl   = (const float*)d_in[12];
    const float* W_out  = (const float*)d_in[13];
    const float* b_out  = (const float*)d_in[14];
    const float* W_g1   = (const float*)d_in[15];
    const float* b_g1   = (const float*)d_in[16];
    const float* W_g2   = (const float*)d_in[17];
    const float* b_g2   = (const float*)d_in[18];
    const float* gamma1 = (const float*)d_in[19];
    const float* beta1  = (const float*)d_in[20];

    float* ws = (float*)d_ws;
    const size_t MS = (size_t)BB * SS * DD;   // 1572864
    float* xn    = ws + 0 * MS;
    float* qf    = ws + 1 * MS;
    float* kf    = ws + 2 * MS;
    float* vl    = ws + 3 * MS;
    float* qo    = ws + 4 * MS;
    float* ko    = ws + 5 * MS;
    float* vo    = ws + 6 * MS;
    float* lin   = ws + 7 * MS;
    float* win   = ws + 8 * MS;
    float* h1    = ws + 9 * MS;
    float* gate  = ws + 10 * MS;
    float* fused = ws + 11 * MS;
    float* kv    = ws + 12 * MS;                       // 2*768*768
    float* attnw = kv + (size_t)BB * DD * DD;          // 24576*65
    float* kfsum = attnw + (size_t)BB * SS * HH * NW;  // 1536
    float* nrm   = kfsum + BB * DD;                    // 2048
    // total ~86.6 MB of d_ws

    const long long SB = (long long)SS * DD;   // per-batch activation stride
    const long long KVB = (long long)DD * DD;  // per-batch kv stride

    // 1. LayerNorm
    ln_kernel<<<dim3(BB * SS), dim3(256), 0, stream>>>(x, gamma1, beta1, xn);

    // 2-7. six projections from xn
    // qf = elu(xn@W_q + b_q)+1
    gemm_f32<<<dim3(12, 32, 1), dim3(256), 0, stream>>>(xn, W_q, b_q, nullptr, nullptr, qf,
        2048, 768, 768, 768, 1, 0, 0, 0, 1, 0);
    gemm_f32<<<dim3(12, 32, 1), dim3(256), 0, stream>>>(xn, W_k, b_k, nullptr, nullptr, kf,
        2048, 768, 768, 768, 1, 0, 0, 0, 1, 0);
    gemm_f32<<<dim3(12, 32, 1), dim3(256), 0, stream>>>(xn, W_v, b_v, nullptr, nullptr, vl,
        2048, 768, 768, 768, 1, 0, 0, 0, 0, 0);
    gemm_f32<<<dim3(12, 32, 1), dim3(256), 0, stream>>>(xn, W_ql, b_ql, nullptr, nullptr, qo,
        2048, 768, 768, 768, 1, 0, 0, 0, 0, 0);
    gemm_f32<<<dim3(12, 32, 1), dim3(256), 0, stream>>>(xn, W_kl, b_kl, nullptr, nullptr, ko,
        2048, 768, 768, 768, 1, 0, 0, 0, 0, 0);
    gemm_f32<<<dim3(12, 32, 1), dim3(256), 0, stream>>>(xn, W_vl, b_vl, nullptr, nullptr, vo,
        2048, 768, 768, 768, 1, 0, 0, 0, 0, 0);

    // 8. kfsum, normalizer
    kfsum_kernel<<<dim3(6), dim3(256), 0, stream>>>(kf, kfsum);
    norm_kernel<<<dim3(2048), dim3(256), 0, stream>>>(qf, kfsum, nrm);

    // 9. kv[b] = kf[b]^T @ vl[b]   (A transposed: sa_m=1, sa_k=768)
    gemm_f32<<<dim3(12, 12, 2), dim3(256), 0, stream>>>(kf, vl, nullptr, nullptr, nullptr, kv,
        768, 768, 1024, 1, 768, SB, SB, KVB, 0, 0);

    // 10. lin[b] = (qf[b] @ kv[b]) / (normalizer + 1e-6)
    gemm_f32<<<dim3(12, 16, 2), dim3(256), 0, stream>>>(qf, kv, nullptr, nrm, nullptr, lin,
        1024, 768, 768, 768, 1, SB, KVB, SB, 0, 0);

    // 11. windowed attention
    attn_score_kernel<<<dim3(96), dim3(256), 0, stream>>>(qo, ko, attnw);
    win_out_kernel<<<dim3(6144), dim3(256), 0, stream>>>(attnw, vo, win);

    // 12. h1 = relu(lin@Wg1a + win@Wg1b + xn@Wg1c + b_g1)  (3 accumulating passes)
    gemm_f32<<<dim3(12, 32, 1), dim3(256), 0, stream>>>(lin, W_g1, nullptr, nullptr, nullptr, h1,
        2048, 768, 768, 768, 1, 0, 0, 0, 0, 0);
    gemm_f32<<<dim3(12, 32, 1), dim3(256), 0, stream>>>(win, W_g1 + (size_t)768 * 768, nullptr, nullptr, nullptr, h1,
        2048, 768, 768, 768, 1, 0, 0, 0, 0, 1);
    gemm_f32<<<dim3(12, 32, 1), dim3(256), 0, stream>>>(xn, W_g1 + (size_t)1536 * 768, b_g1, nullptr, nullptr, h1,
        2048, 768, 768, 768, 1, 0, 0, 0, 2, 1);

    // 13. gate = sigmoid(h1@Wg2 + b_g2)
    gemm_f32<<<dim3(12, 32, 1), dim3(256), 0, stream>>>(h1, W_g2, b_g2, nullptr, nullptr, gate,
        2048, 768, 768, 768, 1, 0, 0, 0, 3, 0);

    // 14. fused = gate*lin + (1-gate)*win
    fuse_kernel<<<dim3(6144), dim3(256), 0, stream>>>(gate, lin, win, fused);

    // 15. out = fused@W_out + b_out + x
    gemm_f32<<<dim3(12, 32, 1), dim3(256), 0, stream>>>(fused, W_out, b_out, nullptr, x, (float*)d_out,
        2048, 768, 768, 768, 1, 0, 0, 0, 0, 0);
}

// Round 2
// 467.431 us; speedup vs baseline: 3.1710x; 3.1710x over previous
//
#include <hip/hip_runtime.h>
#include <math.h>

#define DD 768
#define SS 1024
#define BB 2
#define HH 12
#define DH 64

typedef __attribute__((ext_vector_type(8))) short bf16x8;
typedef __attribute__((ext_vector_type(8))) unsigned short u16x8;
typedef __attribute__((ext_vector_type(4))) float f32x4;

__device__ inline unsigned short f2bf(float f) {
    unsigned int u = __builtin_bit_cast(unsigned int, f);
    unsigned int r = (u + 0x7fffu + ((u >> 16) & 1u)) >> 16;
    return (unsigned short)r;
}
__device__ inline float bf2f(unsigned short h) {
    unsigned int u = ((unsigned int)h) << 16;
    return __builtin_bit_cast(float, u);
}
__device__ inline void gload16(const ushort* g, ushort* l) {
    __builtin_amdgcn_global_load_lds((const __attribute__((address_space(1))) void*)g,
                                     (__attribute__((address_space(3))) void*)l, 16, 0, 0);
}

// ---------------- LayerNorm: writes bf16 into gate_in slice 2 ----------------
__global__ __launch_bounds__(256) void ln_kernel(const float* __restrict__ x,
                                                 const float* __restrict__ gamma,
                                                 const float* __restrict__ beta,
                                                 ushort* __restrict__ gate_in) {
    int row = blockIdx.x;
    const float* xr = x + (size_t)row * DD;
    ushort* outr = gate_in + (size_t)row * 2304 + 1536;
    int tid = threadIdx.x;
    float v[3];
    float s = 0.f, s2 = 0.f;
    #pragma unroll
    for (int r = 0; r < 3; ++r) {
        v[r] = xr[tid + r * 256];
        s += v[r];
        s2 += v[r] * v[r];
    }
    #pragma unroll
    for (int o = 32; o > 0; o >>= 1) {
        s  += __shfl_down(s, o);
        s2 += __shfl_down(s2, o);
    }
    __shared__ float ws1[4], ws2[4];
    int wid = tid >> 6, lane = tid & 63;
    if (lane == 0) { ws1[wid] = s; ws2[wid] = s2; }
    __syncthreads();
    __shared__ float mstat[2];
    if (tid == 0) {
        float a = 0.f, b2 = 0.f;
        #pragma unroll
        for (int i = 0; i < 4; ++i) { a += ws1[i]; b2 += ws2[i]; }
        float mean = a / (float)DD;
        float var = b2 / (float)DD - mean * mean;
        mstat[0] = mean;
        mstat[1] = rsqrtf(var + 1e-5f);
    }
    __syncthreads();
    float mean = mstat[0], rstd = mstat[1];
    #pragma unroll
    for (int r = 0; r < 3; ++r) {
        int i = tid + r * 256;
        outr[i] = f2bf((v[r] - mean) * rstd * gamma[i] + beta[i]);
    }
}

// ---------------- transpose f32 [R][C] -> bf16 [C][R] ----------------
__global__ __launch_bounds__(256) void tr_f32_bf16(const float* __restrict__ in,
                                                   ushort* __restrict__ out,
                                                   int ldi, int ldo,
                                                   long long bIn, long long bOut) {
    __shared__ float t[32][33];
    int z = blockIdx.z;
    int r0 = blockIdx.y * 32, c0 = blockIdx.x * 32;
    int tx = threadIdx.x & 31, ty = threadIdx.x >> 5;
    const float* ip = in + (size_t)z * bIn;
    ushort* op = out + (size_t)z * bOut;
    #pragma unroll
    for (int i = 0; i < 32; i += 8) t[ty + i][tx] = ip[(size_t)(r0 + ty + i) * ldi + c0 + tx];
    __syncthreads();
    #pragma unroll
    for (int i = 0; i < 32; i += 8) op[(size_t)(c0 + ty + i) * ldo + r0 + tx] = f2bf(t[tx][ty + i]);
}

// ---------------- bias concat ----------------
__global__ void bias_cat_kernel(const float* b0, const float* b1, const float* b2,
                                const float* b3, const float* b4, const float* b5,
                                float* __restrict__ out) {
    int i = blockIdx.x * 256 + threadIdx.x;
    if (i >= 4608) return;
    const float* ps[6] = {b0, b1, b2, b3, b4, b5};
    out[i] = ps[i / 768][i % 768];
}

// ---------------- MFMA bf16 GEMM: C = act(A @ B^T + bias) ----------------
// A [M][K] bf16 row-stride lda; B [N][K] bf16 row-stride ldb.
// Tile 128x128, BK=64, 4 waves (2x2), double-buffered LDS via global_load_lds.
// mode 1 = fused projection: act per n-region, Cb only region 0.
__global__ __launch_bounds__(256) void gemm_bf16(
    const ushort* __restrict__ A, const ushort* __restrict__ B,
    float* __restrict__ Cf, ushort* __restrict__ Cb,
    const float* __restrict__ bias, const float* __restrict__ rowdiv,
    const float* __restrict__ addsrc,
    int M, int N, int K, int lda, int ldb, int ldcf, int ldcb,
    long long bA, long long bB, long long bCf, long long bCb,
    int act, int mode) {
    __shared__ ushort As[2][128 * 64];
    __shared__ ushort Bs[2][128 * 64];
    const int tid = threadIdx.x, wid = tid >> 6, lane = tid & 63;
    const int m0 = blockIdx.y * 128, n0 = blockIdx.x * 128, z = blockIdx.z;
    const ushort* Az = A + (size_t)z * bA;
    const ushort* Bz = B + (size_t)z * bB;
    const int srow = lane >> 3, scol = (lane & 7) * 8;
    const int wm = wid >> 1, wn = wid & 1;
    const int fr = lane & 15, fq = lane >> 4;
    f32x4 acc[4][4];
    #pragma unroll
    for (int i = 0; i < 4; ++i)
        #pragma unroll
        for (int j = 0; j < 4; ++j) acc[i][j] = f32x4{0.f, 0.f, 0.f, 0.f};
    int nkt = K >> 6;
    int cur = 0;
    #pragma unroll
    for (int i = 0; i < 4; ++i) {
        int ra = wid * 32 + i * 8 + srow;
        gload16(Az + (size_t)(m0 + ra) * lda + scol, &As[0][(wid * 32 + i * 8) * 64]);
        gload16(Bz + (size_t)(n0 + ra) * ldb + scol, &Bs[0][(wid * 32 + i * 8) * 64]);
    }
    for (int kt = 0; kt < nkt; ++kt) {
        __syncthreads();
        if (kt + 1 < nkt) {
            int k0 = (kt + 1) << 6;
            #pragma unroll
            for (int i = 0; i < 4; ++i) {
                int ra = wid * 32 + i * 8 + srow;
                gload16(Az + (size_t)(m0 + ra) * lda + k0 + scol, &As[cur ^ 1][(wid * 32 + i * 8) * 64]);
                gload16(Bz + (size_t)(n0 + ra) * ldb + k0 + scol, &Bs[cur ^ 1][(wid * 32 + i * 8) * 64]);
            }
        }
        #pragma unroll
        for (int ks = 0; ks < 2; ++ks) {
            bf16x8 af[4], bf[4];
            #pragma unroll
            for (int mf = 0; mf < 4; ++mf)
                af[mf] = *(const bf16x8*)&As[cur][(wm * 64 + mf * 16 + fr) * 64 + ks * 32 + fq * 8];
            #pragma unroll
            for (int nf = 0; nf < 4; ++nf)
                bf[nf] = *(const bf16x8*)&Bs[cur][(wn * 64 + nf * 16 + fr) * 64 + ks * 32 + fq * 8];
            #pragma unroll
            for (int mf = 0; mf < 4; ++mf)
                #pragma unroll
                for (int nf = 0; nf < 4; ++nf)
                    acc[mf][nf] = __builtin_amdgcn_mfma_f32_16x16x32_bf16(af[mf], bf[nf], acc[mf][nf], 0, 0, 0);
        }
        cur ^= 1;
    }
    int region = n0 / 768;
    int eact = act;
    bool wCb = (Cb != nullptr);
    if (mode == 1) { eact = (region < 2) ? 1 : 0; wCb = wCb && (region == 0); }
    float* cfz = Cf ? Cf + (size_t)z * bCf : nullptr;
    ushort* cbz = wCb ? Cb + (size_t)z * bCb : nullptr;
    #pragma unroll
    for (int mf = 0; mf < 4; ++mf) {
        #pragma unroll
        for (int j = 0; j < 4; ++j) {
            int m = m0 + wm * 64 + mf * 16 + fq * 4 + j;
            float rd = rowdiv ? 1.f / (rowdiv[(size_t)z * M + m] + 1e-6f) : 1.f;
            #pragma unroll
            for (int nf = 0; nf < 4; ++nf) {
                int n = n0 + wn * 64 + nf * 16 + fr;
                float v = acc[mf][nf][j];
                if (bias) v += bias[n];
                v *= rd;
                if (eact == 1) v = (v > 0.f) ? v + 1.f : expf(v);
                else if (eact == 2) v = fmaxf(v, 0.f);
                else if (eact == 3) v = 1.f / (1.f + expf(-v));
                if (addsrc) v += addsrc[(size_t)m * ldcf + n];
                if (cfz) cfz[(size_t)m * ldcf + n] = v;
                if (cbz) cbz[(size_t)m * ldcb + n] = f2bf(v);
            }
        }
    }
}

// ---------------- kf column sums (kf = projC region 1, strided) ----------------
__global__ void kfsum_kernel(const float* __restrict__ projC, float* __restrict__ kfsum) {
    int b = blockIdx.x / 3;
    int d = (blockIdx.x % 3) * 256 + threadIdx.x;
    const float* p = projC + (size_t)b * SS * 4608 + 768 + d;
    float s = 0.f;
    for (int i = 0; i < SS; ++i) s += p[(size_t)i * 4608];
    kfsum[b * DD + d] = s;
}

// ---------------- normalizer[b,s] = dot(qf[b,s,:], kfsum[b,:]) ----------------
__global__ __launch_bounds__(256) void norm_kernel(const float* __restrict__ projC,
                                                   const float* __restrict__ kfsum,
                                                   float* __restrict__ nrm) {
    int row = blockIdx.x;
    int b = row / SS;
    const float* q = projC + (size_t)row * 4608;
    const float* ks = kfsum + b * DD;
    int tid = threadIdx.x;
    float s = 0.f;
    for (int i = tid; i < DD; i += 256) s += q[i] * ks[i];
    #pragma unroll
    for (int o = 32; o > 0; o >>= 1) s += __shfl_down(s, o);
    __shared__ float wsum[4];
    int wid = tid >> 6, lane = tid & 63;
    if (lane == 0) wsum[wid] = s;
    __syncthreads();
    if (tid == 0) nrm[row] = wsum[0] + wsum[1] + wsum[2] + wsum[3];
}

// ---------------- fused windowed attention: one wave per (b,s,h) ----------------
__global__ __launch_bounds__(256) void attn_kernel(const float* __restrict__ projC,
                                                   ushort* __restrict__ gate_in) {
    int wv = (blockIdx.x << 2) + (threadIdx.x >> 6);   // 24576 waves
    int lane = threadIdx.x & 63;
    int h = wv % HH;
    int bs = wv / HH;
    int s = bs % SS;
    int b = bs / SS;
    const float* qp = projC + (size_t)(b * SS + s) * 4608 + 2304 + h * DH;
    int idx = s - 32 + lane;
    bool valid = (idx >= 0 && idx < SS);
    const float* kp = projC + (size_t)(b * SS + (valid ? idx : 0)) * 4608 + 3072 + h * DH;
    int i65 = s + 32;
    bool v65 = (i65 < SS);
    const float* k65p = projC + (size_t)(b * SS + (v65 ? i65 : 0)) * 4608 + 3072 + h * DH;
    float sc = 0.f, sc65 = 0.f;
    #pragma unroll
    for (int j = 0; j < 16; ++j) {
        f32x4 q = *(const f32x4*)(qp + j * 4);
        f32x4 kk = *(const f32x4*)(kp + j * 4);
        f32x4 k6 = *(const f32x4*)(k65p + j * 4);
        #pragma unroll
        for (int e = 0; e < 4; ++e) { sc += q[e] * kk[e]; sc65 += q[e] * k6[e]; }
    }
    sc *= 0.125f; sc65 *= 0.125f;
    if (!valid) sc = -1e30f;
    if (!v65) sc65 = -1e30f;
    float m = sc;
    #pragma unroll
    for (int o = 32; o > 0; o >>= 1) m = fmaxf(m, __shfl_xor(m, o));
    m = fmaxf(m, sc65);
    float p = valid ? expf(sc - m) : 0.f;
    float p65 = v65 ? expf(sc65 - m) : 0.f;
    float denom = p;
    #pragma unroll
    for (int o = 32; o > 0; o >>= 1) denom += __shfl_xor(denom, o);
    denom += p65;
    float inv = 1.f / denom;
    const float* vbase = projC + (size_t)(b * SS) * 4608 + 3840 + h * DH + lane;
    float acc = 0.f;
    for (int w = 0; w < 64; ++w) {
        float pw = __shfl(p, w);
        int iw = s - 32 + w;
        if (iw >= 0 && iw < SS) acc += pw * vbase[(size_t)iw * 4608];
    }
    if (v65) acc += p65 * vbase[(size_t)i65 * 4608];
    acc *= inv;
    gate_in[(size_t)(b * SS + s) * 2304 + 768 + h * DH + lane] = f2bf(acc);
}

// ---------------- fused = g*lin + (1-g)*win (bf16 in/out, x8) ----------------
__global__ __launch_bounds__(256) void fuse_kernel(const ushort* __restrict__ gate_in,
                                                   const ushort* __restrict__ gate_bf,
                                                   ushort* __restrict__ fused) {
    int t = blockIdx.x * 256 + threadIdx.x;      // 196608
    int row = t / 96, c8 = (t % 96) * 8;
    const ushort* gi = gate_in + (size_t)row * 2304;
    u16x8 l8 = *(const u16x8*)&gi[c8];
    u16x8 w8 = *(const u16x8*)&gi[768 + c8];
    u16x8 g8 = *(const u16x8*)&gate_bf[(size_t)row * 768 + c8];
    u16x8 o;
    #pragma unroll
    for (int j = 0; j < 8; ++j) {
        float g = bf2f(g8[j]);
        o[j] = f2bf(g * bf2f(l8[j]) + (1.f - g) * bf2f(w8[j]));
    }
    *(u16x8*)&fused[(size_t)row * 768 + c8] = o;
}

extern "C" void kernel_launch(void* const* d_in, const int* in_sizes, int n_in,
                              void* d_out, int out_size, void* d_ws, size_t ws_size,
                              hipStream_t stream) {
    const float* x      = (const float*)d_in[0];
    const float* W_q    = (const float*)d_in[1];
    const float* b_q    = (const float*)d_in[2];
    const float* W_k    = (const float*)d_in[3];
    const float* b_k    = (const float*)d_in[4];
    const float* W_v    = (const float*)d_in[5];
    const float* b_v    = (const float*)d_in[6];
    const float* W_ql   = (const float*)d_in[7];
    const float* b_ql   = (const float*)d_in[8];
    const float* W_kl   = (const float*)d_in[9];
    const float* b_kl   = (const float*)d_in[10];
    const float* W_vl   = (const float*)d_in[11];
    const float* b_vl   = (const float*)d_in[12];
    const float* W_out  = (const float*)d_in[13];
    const float* b_out  = (const float*)d_in[14];
    const float* W_g1   = (const float*)d_in[15];
    const float* b_g1   = (const float*)d_in[16];
    const float* W_g2   = (const float*)d_in[17];
    const float* b_g2   = (const float*)d_in[18];
    const float* gamma1 = (const float*)d_in[19];
    const float* beta1  = (const float*)d_in[20];

    float* projC   = (float*)d_ws;                              // [2048][4608] f32
    ushort* gate_in = (ushort*)(projC + (size_t)2048 * 4608);   // [2048][2304] bf16
    ushort* WprojT  = gate_in + (size_t)2048 * 2304;            // [4608][768]
    ushort* Wg1T    = WprojT + (size_t)4608 * 768;              // [768][2304]
    ushort* Wg2T    = Wg1T + (size_t)768 * 2304;                // [768][768]
    ushort* WoutT   = Wg2T + (size_t)768 * 768;                 // [768][768]
    ushort* qf_bf   = WoutT + (size_t)768 * 768;                // [2048][768]
    ushort* kfT     = qf_bf + (size_t)2048 * 768;               // [2][768][1024]
    ushort* vlT     = kfT + (size_t)2 * 768 * 1024;             // [2][768][1024]
    ushort* kvT     = vlT + (size_t)2 * 768 * 1024;             // [2][768][768]
    ushort* h1_bf   = kvT + (size_t)2 * 768 * 768;              // [2048][768]
    ushort* gate_bf = h1_bf + (size_t)2048 * 768;               // [2048][768]
    ushort* fused_bf= gate_bf + (size_t)2048 * 768;             // [2048][768]
    float* bias_cat = (float*)(fused_bf + (size_t)2048 * 768);  // [4608]
    float* kfsum    = bias_cat + 4608;                          // [1536]
    float* nrm      = kfsum + 1536;                             // [2048]

    const long long W2 = (long long)768 * 768;

    // weight transposes -> bf16 [N][K]
    tr_f32_bf16<<<dim3(24, 24, 1), 256, 0, stream>>>(W_q,  WprojT + 0 * W2, 768, 768, 0, 0);
    tr_f32_bf16<<<dim3(24, 24, 1), 256, 0, stream>>>(W_k,  WprojT + 1 * W2, 768, 768, 0, 0);
    tr_f32_bf16<<<dim3(24, 24, 1), 256, 0, stream>>>(W_v,  WprojT + 2 * W2, 768, 768, 0, 0);
    tr_f32_bf16<<<dim3(24, 24, 1), 256, 0, stream>>>(W_ql, WprojT + 3 * W2, 768, 768, 0, 0);
    tr_f32_bf16<<<dim3(24, 24, 1), 256, 0, stream>>>(W_kl, WprojT + 4 * W2, 768, 768, 0, 0);
    tr_f32_bf16<<<dim3(24, 24, 1), 256, 0, stream>>>(W_vl, WprojT + 5 * W2, 768, 768, 0, 0);
    tr_f32_bf16<<<dim3(24, 72, 1), 256, 0, stream>>>(W_g1, Wg1T, 768, 2304, 0, 0);
    tr_f32_bf16<<<dim3(24, 24, 1), 256, 0, stream>>>(W_g2, Wg2T, 768, 768, 0, 0);
    tr_f32_bf16<<<dim3(24, 24, 1), 256, 0, stream>>>(W_out, WoutT, 768, 768, 0, 0);
    bias_cat_kernel<<<dim3(18), 256, 0, stream>>>(b_q, b_k, b_v, b_ql, b_kl, b_vl, bias_cat);

    // LayerNorm -> gate_in slice 2 (bf16)
    ln_kernel<<<dim3(2048), 256, 0, stream>>>(x, gamma1, beta1, gate_in);

    // fused 6-way projection: [2048][4608] f32 (+ qf bf16 copy)
    gemm_bf16<<<dim3(36, 16, 1), 256, 0, stream>>>(
        gate_in + 1536, WprojT, projC, qf_bf, bias_cat, nullptr, nullptr,
        2048, 4608, 768, 2304, 768, 4608, 768, 0, 0, 0, 0, 0, 1);

    kfsum_kernel<<<dim3(6), 256, 0, stream>>>(projC, kfsum);
    norm_kernel<<<dim3(2048), 256, 0, stream>>>(projC, kfsum, nrm);

    // kf, vl transposes (strided f32 -> bf16 [d][s] per batch)
    tr_f32_bf16<<<dim3(24, 32, 2), 256, 0, stream>>>(projC + 768, kfT, 4608, 1024,
        (long long)1024 * 4608, (long long)768 * 1024);
    tr_f32_bf16<<<dim3(24, 32, 2), 256, 0, stream>>>(projC + 1536, vlT, 4608, 1024,
        (long long)1024 * 4608, (long long)768 * 1024);

    // kvT[b][e][d] = sum_s vl[s][e] kf[s][d]   (bf16 out)
    gemm_bf16<<<dim3(6, 6, 2), 256, 0, stream>>>(
        vlT, kfT, nullptr, kvT, nullptr, nullptr, nullptr,
        768, 768, 1024, 1024, 1024, 768, 768,
        (long long)768 * 1024, (long long)768 * 1024, 0, W2, 0, 0);

    // lin[b][s][e] = (qf[b] @ kvT[b]^T) / nrm  -> gate_in slice 0 (bf16)
    gemm_bf16<<<dim3(6, 8, 2), 256, 0, stream>>>(
        qf_bf, kvT, nullptr, gate_in, nullptr, nrm, nullptr,
        1024, 768, 768, 768, 768, 768, 2304,
        (long long)1024 * 768, W2, 0, (long long)1024 * 2304, 0, 0);

    // windowed attention -> gate_in slice 1 (bf16)
    attn_kernel<<<dim3(6144), 256, 0, stream>>>(projC, gate_in);

    // gate1 = relu(gate_in @ Wg1T^T + b_g1) -> h1 (bf16)
    gemm_bf16<<<dim3(6, 16, 1), 256, 0, stream>>>(
        gate_in, Wg1T, nullptr, h1_bf, b_g1, nullptr, nullptr,
        2048, 768, 2304, 2304, 2304, 768, 768, 0, 0, 0, 0, 2, 0);

    // gate = sigmoid(h1 @ Wg2T^T + b_g2) -> gate_bf
    gemm_bf16<<<dim3(6, 16, 1), 256, 0, stream>>>(
        h1_bf, Wg2T, nullptr, gate_bf, b_g2, nullptr, nullptr,
        2048, 768, 768, 768, 768, 768, 768, 0, 0, 0, 0, 3, 0);

    // fused = g*lin + (1-g)*win
    fuse_kernel<<<dim3(768), 256, 0, stream>>>(gate_in, gate_bf, fused_bf);

    // out = fused @ WoutT^T + b_out + x  (f32)
    gemm_bf16<<<dim3(6, 16, 1), 256, 0, stream>>>(
        fused_bf, WoutT, (float*)d_out, nullptr, b_out, nullptr, x,
        2048, 768, 768, 768, 768, 768, 768, 0, 0, 0, 0, 0, 0);
}

// Round 3
// 224.524 us; speedup vs baseline: 6.6016x; 2.0819x over previous
//
#include <hip/hip_runtime.h>
#include <math.h>

#define DD 768
#define SS 1024
#define BB 2
#define HH 12
#define DH 64

typedef __attribute__((ext_vector_type(8))) short bf16x8;
typedef __attribute__((ext_vector_type(8))) unsigned short u16x8;
typedef __attribute__((ext_vector_type(4))) float f32x4;

// ---- workspace layout (ushort units) ----
constexpr size_t O_GATEIN = 0;                                   // [2048][2304] bf16
constexpr size_t O_WPROJT = O_GATEIN + (size_t)2048 * 2304;      // [4608][768]
constexpr size_t O_WG1T   = O_WPROJT + (size_t)4608 * 768;       // [768][2304]
constexpr size_t O_WG2T   = O_WG1T + (size_t)768 * 2304;         // [768][768]
constexpr size_t O_WOUTT  = O_WG2T + (size_t)768 * 768;          // [768][768]
constexpr size_t O_QF     = O_WOUTT + (size_t)768 * 768;         // [2048][768]
constexpr size_t O_KVT    = O_QF + (size_t)2048 * 768;           // [2][768][768]
constexpr size_t O_KFT    = O_KVT + (size_t)2 * 768 * 768;       // [2][768][1024]
constexpr size_t O_VLT    = O_KFT + (size_t)2 * 768 * 1024;      // [2][768][1024]
constexpr size_t O_QOH    = O_VLT + (size_t)2 * 768 * 1024;      // [2][12][1024][64]
constexpr size_t O_KOH    = O_QOH + (size_t)2 * 12 * 1024 * 64;  // [2][12][1024][64]
constexpr size_t O_VOT    = O_KOH + (size_t)2 * 12 * 1024 * 64;  // [2][12][64][1024]
constexpr size_t O_H1     = O_VOT + (size_t)2 * 12 * 64 * 1024;  // [2048][768]
constexpr size_t O_FUSED  = O_H1 + (size_t)2048 * 768;           // [2048][768]
constexpr size_t O_F32    = O_FUSED + (size_t)2048 * 768;        // f32 area

__device__ inline unsigned short f2bf(float f) {
    unsigned int u = __builtin_bit_cast(unsigned int, f);
    unsigned int r = (u + 0x7fffu + ((u >> 16) & 1u)) >> 16;
    return (unsigned short)r;
}
__device__ inline float bf2f(unsigned short h) {
    unsigned int u = ((unsigned int)h) << 16;
    return __builtin_bit_cast(float, u);
}
__device__ inline void gload16(const ushort* g, ushort* l) {
    __builtin_amdgcn_global_load_lds((const __attribute__((address_space(1))) void*)g,
                                     (__attribute__((address_space(3))) void*)l, 16, 0, 0);
}

// ---------------- LayerNorm -> gate_in slice 2 (bf16) ----------------
__global__ __launch_bounds__(256) void ln_kernel(const float* __restrict__ x,
                                                 const float* __restrict__ gamma,
                                                 const float* __restrict__ beta,
                                                 ushort* __restrict__ wsb) {
    int row = blockIdx.x;
    const float* xr = x + (size_t)row * DD;
    ushort* outr = wsb + O_GATEIN + (size_t)row * 2304 + 1536;
    int tid = threadIdx.x;
    float v[3];
    float s = 0.f, s2 = 0.f;
    #pragma unroll
    for (int r = 0; r < 3; ++r) {
        v[r] = xr[tid + r * 256];
        s += v[r];
        s2 += v[r] * v[r];
    }
    #pragma unroll
    for (int o = 32; o > 0; o >>= 1) {
        s  += __shfl_down(s, o);
        s2 += __shfl_down(s2, o);
    }
    __shared__ float ws1[4], ws2[4];
    int wid = tid >> 6, lane = tid & 63;
    if (lane == 0) { ws1[wid] = s; ws2[wid] = s2; }
    __syncthreads();
    __shared__ float mstat[2];
    if (tid == 0) {
        float a = 0.f, b2 = 0.f;
        #pragma unroll
        for (int i = 0; i < 4; ++i) { a += ws1[i]; b2 += ws2[i]; }
        float mean = a / (float)DD;
        float var = b2 / (float)DD - mean * mean;
        mstat[0] = mean;
        mstat[1] = rsqrtf(var + 1e-5f);
    }
    __syncthreads();
    float mean = mstat[0], rstd = mstat[1];
    #pragma unroll
    for (int r = 0; r < 3; ++r) {
        int i = tid + r * 256;
        outr[i] = f2bf((v[r] - mean) * rstd * gamma[i] + beta[i]);
    }
}

// ---------------- all weight transposes in one dispatch ----------------
struct TrArgs {
    const float* src[11];
    unsigned long long dstOff[11];
    int ldo[11];
};
__global__ __launch_bounds__(256) void tr_all(TrArgs a, ushort* __restrict__ wsb) {
    __shared__ float t[32][33];
    int z = blockIdx.z;
    const float* ip = a.src[z];
    ushort* op = wsb + a.dstOff[z];
    int ldo = a.ldo[z];
    int r0 = blockIdx.y * 32, c0 = blockIdx.x * 32;
    int tx = threadIdx.x & 31, ty = threadIdx.x >> 5;
    #pragma unroll
    for (int i = 0; i < 32; i += 8) t[ty + i][tx] = ip[(size_t)(r0 + ty + i) * 768 + c0 + tx];
    __syncthreads();
    #pragma unroll
    for (int i = 0; i < 32; i += 8) op[(size_t)(c0 + ty + i) * ldo + r0 + tx] = f2bf(t[tx][ty + i]);
}

__global__ void bias_cat_kernel(const float* b0, const float* b1, const float* b2,
                                const float* b3, const float* b4, const float* b5,
                                float* __restrict__ out) {
    int i = blockIdx.x * 256 + threadIdx.x;
    if (i >= 4608) return;
    const float* ps[6] = {b0, b1, b2, b3, b4, b5};
    out[i] = ps[i / 768][i % 768];
}

// ---------------- MFMA bf16 GEMM (TM x 128 tile, BK=64, dbuf) ----------------
// mode 0: plain (Cf/Cb row-major, bias/rowdiv/act/addsrc)
// mode 1: fused projection scatter epilogue
// mode 2: gate2 + fuse (v=sigmoid -> fused = v*lin + (1-v)*win)
template<int TM>
__global__ __launch_bounds__(256) void gemm_bf16(
    const ushort* __restrict__ A, const ushort* __restrict__ B,
    ushort* __restrict__ wsb,
    float* __restrict__ Cf, ushort* __restrict__ Cb,
    const float* __restrict__ bias, const float* __restrict__ rowdiv,
    const float* __restrict__ addsrc,
    int M, int N, int K, int lda, int ldb, int ldcf, int ldcb,
    long long bA, long long bB, long long bCf, long long bCb,
    int act, int mode) {
    constexpr int MF = TM / 32;
    __shared__ __align__(16) ushort As[2][TM * 64];
    __shared__ __align__(16) ushort Bs[2][128 * 64];
    const int tid = threadIdx.x, wid = tid >> 6, lane = tid & 63;
    const int m0 = blockIdx.y * TM, n0 = blockIdx.x * 128, z = blockIdx.z;
    const ushort* Az = A + (size_t)z * bA;
    const ushort* Bz = B + (size_t)z * bB;
    const int srow = lane >> 3, scol = (lane & 7) * 8;
    const int wm = wid >> 1, wn = wid & 1;
    const int fr = lane & 15, fq = lane >> 4;
    f32x4 acc[MF][4];
    #pragma unroll
    for (int i = 0; i < MF; ++i)
        #pragma unroll
        for (int j = 0; j < 4; ++j) acc[i][j] = f32x4{0.f, 0.f, 0.f, 0.f};
    int nkt = K >> 6;
    #pragma unroll
    for (int i = 0; i < TM / 32; ++i) {
        int ra = wid * (TM / 4) + i * 8 + srow;
        gload16(Az + (size_t)(m0 + ra) * lda + scol, &As[0][(wid * (TM / 4) + i * 8) * 64]);
    }
    #pragma unroll
    for (int i = 0; i < 4; ++i) {
        int rb = wid * 32 + i * 8 + srow;
        gload16(Bz + (size_t)(n0 + rb) * ldb + scol, &Bs[0][(wid * 32 + i * 8) * 64]);
    }
    int cur = 0;
    for (int kt = 0; kt < nkt; ++kt) {
        __syncthreads();
        if (kt + 1 < nkt) {
            int k0 = (kt + 1) << 6;
            #pragma unroll
            for (int i = 0; i < TM / 32; ++i) {
                int ra = wid * (TM / 4) + i * 8 + srow;
                gload16(Az + (size_t)(m0 + ra) * lda + k0 + scol, &As[cur ^ 1][(wid * (TM / 4) + i * 8) * 64]);
            }
            #pragma unroll
            for (int i = 0; i < 4; ++i) {
                int rb = wid * 32 + i * 8 + srow;
                gload16(Bz + (size_t)(n0 + rb) * ldb + k0 + scol, &Bs[cur ^ 1][(wid * 32 + i * 8) * 64]);
            }
        }
        #pragma unroll
        for (int ks = 0; ks < 2; ++ks) {
            bf16x8 af[MF], bfr[4];
            #pragma unroll
            for (int mf = 0; mf < MF; ++mf)
                af[mf] = *(const bf16x8*)&As[cur][(wm * (TM / 2) + mf * 16 + fr) * 64 + ks * 32 + fq * 8];
            #pragma unroll
            for (int nf = 0; nf < 4; ++nf)
                bfr[nf] = *(const bf16x8*)&Bs[cur][(wn * 64 + nf * 16 + fr) * 64 + ks * 32 + fq * 8];
            #pragma unroll
            for (int mf = 0; mf < MF; ++mf)
                #pragma unroll
                for (int nf = 0; nf < 4; ++nf)
                    acc[mf][nf] = __builtin_amdgcn_mfma_f32_16x16x32_bf16(af[mf], bfr[nf], acc[mf][nf], 0, 0, 0);
        }
        cur ^= 1;
    }

    if (mode == 1) {
        int region = n0 / 768;
        int ncol = n0 - region * 768;
        #pragma unroll
        for (int mf = 0; mf < MF; ++mf) {
            int mbase = m0 + wm * (TM / 2) + mf * 16 + fq * 4;
            int b = mbase >> 10, s0 = mbase & 1023;
            #pragma unroll
            for (int nf = 0; nf < 4; ++nf) {
                int n = n0 + wn * 64 + nf * 16 + fr;
                int nr = ncol + wn * 64 + nf * 16 + fr;
                float bs = bias[n];
                float v[4];
                #pragma unroll
                for (int j = 0; j < 4; ++j) {
                    float t = acc[mf][nf][j] + bs;
                    if (region <= 1) t = (t > 0.f) ? t + 1.f : expf(t);
                    v[j] = t;
                }
                if (region == 0) {
                    #pragma unroll
                    for (int j = 0; j < 4; ++j)
                        wsb[O_QF + (size_t)(mbase + j) * 768 + nr] = f2bf(v[j]);
                } else if (region == 1 || region == 2 || region == 5) {
                    unsigned long long pk = 0;
                    #pragma unroll
                    for (int j = 0; j < 4; ++j)
                        pk |= (unsigned long long)f2bf(v[j]) << (16 * j);
                    size_t rowb;
                    if (region == 1) rowb = O_KFT + (size_t)(b * 768 + nr) * 1024;
                    else if (region == 2) rowb = O_VLT + (size_t)(b * 768 + nr) * 1024;
                    else {
                        int h = nr >> 6, dh = nr & 63;
                        rowb = O_VOT + (size_t)((b * 12 + h) * 64 + dh) * 1024;
                    }
                    *(unsigned long long*)&wsb[rowb + s0] = pk;
                } else {  // 3,4: head-major [bh][s][64]
                    int h = nr >> 6, dh = nr & 63;
                    size_t base = ((region == 3) ? O_QOH : O_KOH) + ((size_t)(b * 12 + h) * 1024) * 64 + dh;
                    #pragma unroll
                    for (int j = 0; j < 4; ++j)
                        wsb[base + (size_t)(s0 + j) * 64] = f2bf(v[j]);
                }
            }
        }
        return;
    }

    float* cfz = Cf ? Cf + (size_t)z * bCf : nullptr;
    ushort* cbz = Cb ? Cb + (size_t)z * bCb : nullptr;
    #pragma unroll
    for (int mf = 0; mf < MF; ++mf) {
        #pragma unroll
        for (int j = 0; j < 4; ++j) {
            int m = m0 + wm * (TM / 2) + mf * 16 + fq * 4 + j;
            float rd = rowdiv ? 1.f / (rowdiv[(size_t)z * M + m] + 1e-6f) : 1.f;
            #pragma unroll
            for (int nf = 0; nf < 4; ++nf) {
                int n = n0 + wn * 64 + nf * 16 + fr;
                float v = acc[mf][nf][j];
                if (bias) v += bias[n];
                v *= rd;
                if (act == 1) v = (v > 0.f) ? v + 1.f : expf(v);
                else if (act == 2) v = fmaxf(v, 0.f);
                else if (act == 3) v = 1.f / (1.f + expf(-v));
                if (mode == 2) {
                    float lin = bf2f(wsb[O_GATEIN + (size_t)m * 2304 + n]);
                    float win = bf2f(wsb[O_GATEIN + (size_t)m * 2304 + 768 + n]);
                    v = v * lin + (1.f - v) * win;
                }
                if (addsrc) v += addsrc[(size_t)m * ldcf + n];
                if (cfz) cfz[(size_t)m * ldcf + n] = v;
                if (cbz) cbz[(size_t)m * ldcb + n] = f2bf(v);
            }
        }
    }
}

// ---------------- kfsum: wave per row of kfT ----------------
__global__ __launch_bounds__(256) void kfsum_kernel(const ushort* __restrict__ wsb,
                                                    float* __restrict__ kfsum) {
    int row = blockIdx.x * 4 + (threadIdx.x >> 6);   // 1536 rows
    int lane = threadIdx.x & 63;
    const ushort* p = wsb + O_KFT + (size_t)row * 1024 + lane * 16;
    float s = 0.f;
    #pragma unroll
    for (int r = 0; r < 2; ++r) {
        u16x8 v = *(const u16x8*)&p[r * 8];
        #pragma unroll
        for (int j = 0; j < 8; ++j) s += bf2f(v[j]);
    }
    #pragma unroll
    for (int o = 32; o > 0; o >>= 1) s += __shfl_xor(s, o);
    if (lane == 0) kfsum[row] = s;
}

// ---------------- normalizer[b,s] = qf . kfsum[b] ----------------
__global__ __launch_bounds__(256) void norm_kernel(const ushort* __restrict__ wsb,
                                                   const float* __restrict__ kfsum,
                                                   float* __restrict__ nrm) {
    int row = blockIdx.x;
    int b = row >> 10;
    const ushort* q = wsb + O_QF + (size_t)row * 768;
    const float* ks = kfsum + b * 768;
    int tid = threadIdx.x;
    float s = 0.f;
    #pragma unroll
    for (int r = 0; r < 3; ++r) {
        int i = tid + r * 256;
        s += bf2f(q[i]) * ks[i];
    }
    #pragma unroll
    for (int o = 32; o > 0; o >>= 1) s += __shfl_down(s, o);
    __shared__ float wsum[4];
    int wid = tid >> 6, lane = tid & 63;
    if (lane == 0) wsum[wid] = s;
    __syncthreads();
    if (tid == 0) nrm[row] = wsum[0] + wsum[1] + wsum[2] + wsum[3];
}

// ---------------- MFMA windowed attention ----------------
// block = (qtile 64, h, b); 4 waves; wave owns 16 q rows. Barrier-free.
__global__ __launch_bounds__(256) void attn_mfma(ushort* __restrict__ wsb) {
    __shared__ __align__(16) ushort Ps[4 * 2048];   // per-wave [16 rows][128 keys] swizzled
    int wq = threadIdx.x >> 6, lane = threadIdx.x & 63;
    int fq = lane >> 4, fr = lane & 15;
    int q0 = blockIdx.x * 64;
    int h = blockIdx.y, b = blockIdx.z;
    int bh = b * HH + h;
    const ushort* Qb = wsb + O_QOH + (size_t)bh * 65536;
    const ushort* Kb = wsb + O_KOH + (size_t)bh * 65536;
    const ushort* Vb = wsb + O_VOT + (size_t)bh * 65536;

    int qrow = q0 + wq * 16 + fr;
    bf16x8 aq0 = *(const bf16x8*)&Qb[(size_t)qrow * 64 + fq * 8];
    bf16x8 aq1 = *(const bf16x8*)&Qb[(size_t)qrow * 64 + 32 + fq * 8];

    f32x4 sc[8];
    #pragma unroll
    for (int nf = 0; nf < 8; ++nf) sc[nf] = f32x4{0.f, 0.f, 0.f, 0.f};
    #pragma unroll
    for (int nf = 0; nf < 8; ++nf) {
        int kr = q0 - 32 + nf * 16 + fr;
        int kc = kr < 0 ? 0 : (kr > 1023 ? 1023 : kr);
        bf16x8 bk0 = *(const bf16x8*)&Kb[(size_t)kc * 64 + fq * 8];
        bf16x8 bk1 = *(const bf16x8*)&Kb[(size_t)kc * 64 + 32 + fq * 8];
        sc[nf] = __builtin_amdgcn_mfma_f32_16x16x32_bf16(aq0, bk0, sc[nf], 0, 0, 0);
        sc[nf] = __builtin_amdgcn_mfma_f32_16x16x32_bf16(aq1, bk1, sc[nf], 0, 0, 0);
    }

    // softmax per row j (band mask); reduce across fr-group via shfl_xor
    float p[8][4];
    float inv[4];
    #pragma unroll
    for (int j = 0; j < 4; ++j) {
        int qt = wq * 16 + fq * 4 + j;
        float sv[8];
        float mx = -1e30f;
        #pragma unroll
        for (int nf = 0; nf < 8; ++nf) {
            int c = nf * 16 + fr;
            int kg = q0 - 32 + c;
            bool val = (c >= qt) && (c <= qt + 64) && (kg >= 0) && (kg < SS);
            float t = sc[nf][j] * 0.125f;
            sv[nf] = val ? t : -1e30f;
            mx = fmaxf(mx, sv[nf]);
        }
        mx = fmaxf(mx, __shfl_xor(mx, 1));
        mx = fmaxf(mx, __shfl_xor(mx, 2));
        mx = fmaxf(mx, __shfl_xor(mx, 4));
        mx = fmaxf(mx, __shfl_xor(mx, 8));
        float dn = 0.f;
        #pragma unroll
        for (int nf = 0; nf < 8; ++nf) {
            float e = expf(sv[nf] - mx);
            p[nf][j] = e;
            dn += e;
        }
        dn += __shfl_xor(dn, 1);
        dn += __shfl_xor(dn, 2);
        dn += __shfl_xor(dn, 4);
        dn += __shfl_xor(dn, 8);
        inv[j] = 1.f / dn;
    }

    // write P to LDS (chunk XOR row swizzle)
    #pragma unroll
    for (int nf = 0; nf < 8; ++nf) {
        int chunk = nf * 2 + (fr >> 3);
        #pragma unroll
        for (int j = 0; j < 4; ++j) {
            int r = fq * 4 + j;
            Ps[wq * 2048 + r * 128 + ((chunk ^ r) * 8) + (fr & 7)] = f2bf(p[nf][j] * inv[j]);
        }
    }
    __syncthreads();

    // PV: A = P[16q][128k] from LDS, B = V^T[d][k] from global
    f32x4 oa[4];
    #pragma unroll
    for (int nf = 0; nf < 4; ++nf) oa[nf] = f32x4{0.f, 0.f, 0.f, 0.f};
    #pragma unroll
    for (int ks = 0; ks < 4; ++ks) {
        bf16x8 pa = *(const bf16x8*)&Ps[wq * 2048 + fr * 128 + (((ks * 4 + fq) ^ fr) * 8)];
        #pragma unroll
        for (int nf = 0; nf < 4; ++nf) {
            int dr = nf * 16 + fr;
            const ushort* vp = Vb + (ptrdiff_t)dr * 1024 + (q0 - 32 + ks * 32 + fq * 8);
            bf16x8 bv = *(const bf16x8*)vp;
            oa[nf] = __builtin_amdgcn_mfma_f32_16x16x32_bf16(pa, bv, oa[nf], 0, 0, 0);
        }
    }

    // write win_out -> gate_in slice 1
    #pragma unroll
    for (int nf = 0; nf < 4; ++nf) {
        int d = nf * 16 + fr;
        #pragma unroll
        for (int j = 0; j < 4; ++j) {
            int q = q0 + wq * 16 + fq * 4 + j;
            wsb[O_GATEIN + (size_t)(b * SS + q) * 2304 + 768 + h * 64 + d] = f2bf(oa[nf][j]);
        }
    }
}

extern "C" void kernel_launch(void* const* d_in, const int* in_sizes, int n_in,
                              void* d_out, int out_size, void* d_ws, size_t ws_size,
                              hipStream_t stream) {
    const float* x      = (const float*)d_in[0];
    const float* W_q    = (const float*)d_in[1];
    const float* b_q    = (const float*)d_in[2];
    const float* W_k    = (const float*)d_in[3];
    const float* b_k    = (const float*)d_in[4];
    const float* W_v    = (const float*)d_in[5];
    const float* b_v    = (const float*)d_in[6];
    const float* W_ql   = (const float*)d_in[7];
    const float* b_ql   = (const float*)d_in[8];
    const float* W_kl   = (const float*)d_in[9];
    const float* b_kl   = (const float*)d_in[10];
    const float* W_vl   = (const float*)d_in[11];
    const float* b_vl   = (const float*)d_in[12];
    const float* W_out  = (const float*)d_in[13];
    const float* b_out  = (const float*)d_in[14];
    const float* W_g1   = (const float*)d_in[15];
    const float* b_g1   = (const float*)d_in[16];
    const float* W_g2   = (const float*)d_in[17];
    const float* b_g2   = (const float*)d_in[18];
    const float* gamma1 = (const float*)d_in[19];
    const float* beta1  = (const float*)d_in[20];

    ushort* wsb = (ushort*)d_ws;
    float* f32a = (float*)(wsb + O_F32);
    float* bias_cat = f32a;            // 4608
    float* kfsum    = f32a + 4608;     // 1536
    float* nrm      = kfsum + 1536;    // 2048

    const long long W2 = (long long)768 * 768;

    // 1. all weight transposes (one dispatch)
    TrArgs ta;
    const float* wsrc[6] = {W_q, W_k, W_v, W_ql, W_kl, W_vl};
    for (int i = 0; i < 6; ++i) { ta.src[i] = wsrc[i]; ta.dstOff[i] = O_WPROJT + i * W2; ta.ldo[i] = 768; }
    for (int i = 0; i < 3; ++i) { ta.src[6 + i] = W_g1 + (size_t)i * 768 * 768; ta.dstOff[6 + i] = O_WG1T + i * 768; ta.ldo[6 + i] = 2304; }
    ta.src[9] = W_g2;  ta.dstOff[9] = O_WG2T;  ta.ldo[9] = 768;
    ta.src[10] = W_out; ta.dstOff[10] = O_WOUTT; ta.ldo[10] = 768;
    tr_all<<<dim3(24, 24, 11), 256, 0, stream>>>(ta, wsb);
    bias_cat_kernel<<<dim3(18), 256, 0, stream>>>(b_q, b_k, b_v, b_ql, b_kl, b_vl, bias_cat);

    // 2. LayerNorm -> gate_in slice 2
    ln_kernel<<<dim3(2048), 256, 0, stream>>>(x, gamma1, beta1, wsb);

    // 3. fused 6-way projection (mode 1 scatter epilogue)
    gemm_bf16<128><<<dim3(36, 16, 1), 256, 0, stream>>>(
        wsb + O_GATEIN + 1536, wsb + O_WPROJT, wsb, nullptr, nullptr, bias_cat, nullptr, nullptr,
        2048, 4608, 768, 2304, 768, 0, 0, 0, 0, 0, 0, 0, 1);

    // 4. kfsum + normalizer
    kfsum_kernel<<<dim3(384), 256, 0, stream>>>(wsb, kfsum);
    norm_kernel<<<dim3(2048), 256, 0, stream>>>(wsb, kfsum, nrm);

    // 5. kvT[b][e][d] = sum_s vl[s,e] kf[s,d]
    gemm_bf16<64><<<dim3(6, 12, 2), 256, 0, stream>>>(
        wsb + O_VLT, wsb + O_KFT, wsb, nullptr, wsb + O_KVT, nullptr, nullptr, nullptr,
        768, 768, 1024, 1024, 1024, 0, 768,
        (long long)768 * 1024, (long long)768 * 1024, 0, W2, 0, 0);

    // 6. lin = (qf @ kvT^T)/nrm -> gate_in slice 0
    gemm_bf16<64><<<dim3(6, 16, 2), 256, 0, stream>>>(
        wsb + O_QF, wsb + O_KVT, wsb, nullptr, wsb + O_GATEIN, nullptr, nrm, nullptr,
        1024, 768, 768, 768, 768, 0, 2304,
        (long long)1024 * 768, W2, 0, (long long)1024 * 2304, 0, 0);

    // 7. windowed attention -> gate_in slice 1
    attn_mfma<<<dim3(16, 12, 2), 256, 0, stream>>>(wsb);

    // 8. h1 = relu(gate_in @ Wg1T^T + b_g1)
    gemm_bf16<64><<<dim3(6, 32, 1), 256, 0, stream>>>(
        wsb + O_GATEIN, wsb + O_WG1T, wsb, nullptr, wsb + O_H1, b_g1, nullptr, nullptr,
        2048, 768, 2304, 2304, 2304, 0, 768, 0, 0, 0, 0, 2, 0);

    // 9. gate = sigmoid(h1 @ Wg2T^T + b_g2); fused = g*lin + (1-g)*win  (mode 2)
    gemm_bf16<64><<<dim3(6, 32, 1), 256, 0, stream>>>(
        wsb + O_H1, wsb + O_WG2T, wsb, nullptr, wsb + O_FUSED, b_g2, nullptr, nullptr,
        2048, 768, 768, 768, 768, 0, 768, 0, 0, 0, 0, 3, 2);

    // 10. out = fused @ WoutT^T + b_out + x
    gemm_bf16<64><<<dim3(6, 32, 1), 256, 0, stream>>>(
        wsb + O_FUSED, wsb + O_WOUTT, wsb, (float*)d_out, nullptr, b_out, nullptr, x,
        2048, 768, 768, 768, 768, 768, 0, 0, 0, (long long)0, 0, 0, 0);
}

// Round 4
// 191.832 us; speedup vs baseline: 7.7266x; 1.1704x over previous
//
#include <hip/hip_runtime.h>
#include <math.h>

#define DD 768
#define SS 1024
#define BB 2
#define HH 12
#define DH 64

typedef __attribute__((ext_vector_type(8))) short bf16x8;
typedef __attribute__((ext_vector_type(8))) unsigned short u16x8;
typedef __attribute__((ext_vector_type(4))) float f32x4;

// ---- workspace layout (ushort units) ----
constexpr size_t O_GATEIN = 0;                                   // [2048][2304] bf16
constexpr size_t O_WPROJT = O_GATEIN + (size_t)2048 * 2304;      // [4608][768]
constexpr size_t O_WG1T   = O_WPROJT + (size_t)4608 * 768;       // [768][2304]
constexpr size_t O_WG2T   = O_WG1T + (size_t)768 * 2304;         // [768][768]
constexpr size_t O_WOUTT  = O_WG2T + (size_t)768 * 768;          // [768][768]
constexpr size_t O_PROJ   = O_WOUTT + (size_t)768 * 768;         // [2048][4608] (regions 0,3,4 used)
constexpr size_t O_KFT    = O_PROJ + (size_t)2048 * 4608;        // [2][768][1024]
constexpr size_t O_VLT    = O_KFT + (size_t)2 * 768 * 1024;      // [2][768][1024]
constexpr size_t O_VOT    = O_VLT + (size_t)2 * 768 * 1024;      // [2][12][64][1024]
constexpr size_t O_KVT    = O_VOT + (size_t)2 * 768 * 1024;      // [2][768][768]
constexpr size_t O_H1     = O_KVT + (size_t)2 * 768 * 768;       // [2048][768]
constexpr size_t O_FUSED  = O_H1 + (size_t)2048 * 768;           // [2048][768]
constexpr size_t O_F32    = O_FUSED + (size_t)2048 * 768;        // f32 area

__device__ inline unsigned short f2bf(float f) {
    unsigned int u = __builtin_bit_cast(unsigned int, f);
    unsigned int r = (u + 0x7fffu + ((u >> 16) & 1u)) >> 16;
    return (unsigned short)r;
}
__device__ inline float bf2f(unsigned short h) {
    unsigned int u = ((unsigned int)h) << 16;
    return __builtin_bit_cast(float, u);
}
__device__ inline void gload16(const ushort* g, ushort* l) {
    __builtin_amdgcn_global_load_lds((const __attribute__((address_space(1))) void*)g,
                                     (__attribute__((address_space(3))) void*)l, 16, 0, 0);
}

// ---------------- LayerNorm -> gate_in slice 2 (bf16) ----------------
__global__ __launch_bounds__(256) void ln_kernel(const float* __restrict__ x,
                                                 const float* __restrict__ gamma,
                                                 const float* __restrict__ beta,
                                                 ushort* __restrict__ wsb) {
    int row = blockIdx.x;
    const float* xr = x + (size_t)row * DD;
    ushort* outr = wsb + O_GATEIN + (size_t)row * 2304 + 1536;
    int tid = threadIdx.x;
    float v[3];
    float s = 0.f, s2 = 0.f;
    #pragma unroll
    for (int r = 0; r < 3; ++r) {
        v[r] = xr[tid + r * 256];
        s += v[r];
        s2 += v[r] * v[r];
    }
    #pragma unroll
    for (int o = 32; o > 0; o >>= 1) {
        s  += __shfl_down(s, o);
        s2 += __shfl_down(s2, o);
    }
    __shared__ float ws1[4], ws2[4];
    int wid = tid >> 6, lane = tid & 63;
    if (lane == 0) { ws1[wid] = s; ws2[wid] = s2; }
    __syncthreads();
    __shared__ float mstat[2];
    if (tid == 0) {
        float a = 0.f, b2 = 0.f;
        #pragma unroll
        for (int i = 0; i < 4; ++i) { a += ws1[i]; b2 += ws2[i]; }
        float mean = a / (float)DD;
        float var = b2 / (float)DD - mean * mean;
        mstat[0] = mean;
        mstat[1] = rsqrtf(var + 1e-5f);
    }
    __syncthreads();
    float mean = mstat[0], rstd = mstat[1];
    #pragma unroll
    for (int r = 0; r < 3; ++r) {
        int i = tid + r * 256;
        outr[i] = f2bf((v[r] - mean) * rstd * gamma[i] + beta[i]);
    }
}

// ---------------- all weight transposes in one dispatch ----------------
struct TrArgs {
    const float* src[11];
    unsigned long long dstOff[11];
    int ldo[11];
};
__global__ __launch_bounds__(256) void tr_all(TrArgs a, ushort* __restrict__ wsb) {
    __shared__ float t[32][33];
    int z = blockIdx.z;
    const float* ip = a.src[z];
    ushort* op = wsb + a.dstOff[z];
    int ldo = a.ldo[z];
    int r0 = blockIdx.y * 32, c0 = blockIdx.x * 32;
    int tx = threadIdx.x & 31, ty = threadIdx.x >> 5;
    #pragma unroll
    for (int i = 0; i < 32; i += 8) t[ty + i][tx] = ip[(size_t)(r0 + ty + i) * 768 + c0 + tx];
    __syncthreads();
    #pragma unroll
    for (int i = 0; i < 32; i += 8) op[(size_t)(c0 + ty + i) * ldo + r0 + tx] = f2bf(t[tx][ty + i]);
}

__global__ void bias_cat_kernel(const float* b0, const float* b1, const float* b2,
                                const float* b3, const float* b4, const float* b5,
                                float* __restrict__ out) {
    int i = blockIdx.x * 256 + threadIdx.x;
    if (i >= 4608) return;
    const float* ps[6] = {b0, b1, b2, b3, b4, b5};
    out[i] = ps[i / 768][i % 768];
}

// ---------------- MFMA bf16 GEMM (TM x 128 tile, BK=64, single-buffer m97 structure) ----------------
// T2 swizzle: staging source col XOR'd with row&7; fragment reads XOR back.
// mode 0: plain epilogue (Cf/Cb row-major, bias/rowdiv/act)
// mode 1: fused projection epilogue (regions 0,3,4 row-major into proj; 1,2,5 LDS-transposed)
// mode 2: gate2 + fuse
template<int TM>
__global__ __launch_bounds__(256) void gemm_bf16(
    const ushort* __restrict__ A, const ushort* __restrict__ B,
    ushort* __restrict__ wsb,
    float* __restrict__ Cf, ushort* __restrict__ Cb,
    const float* __restrict__ bias, const float* __restrict__ rowdiv,
    const float* __restrict__ addsrc,
    int M, int N, int K, int lda, int ldb, int ldcf, int ldcb,
    long long bA, long long bB, long long bCf, long long bCb,
    int act, int mode) {
    constexpr int MF = TM / 32;
    constexpr int LDSN = (TM == 128) ? (128 * 136) : (TM * 64 + 128 * 64);
    __shared__ __align__(16) ushort lds[LDSN];
    ushort* As = lds;
    ushort* Bs = lds + TM * 64;
    const int tid = threadIdx.x, wid = tid >> 6, lane = tid & 63;
    const int m0 = blockIdx.y * TM, n0 = blockIdx.x * 128, z = blockIdx.z;
    const ushort* Az = A + (size_t)z * bA;
    const ushort* Bz = B + (size_t)z * bB;
    const int srow = lane >> 3;
    const int scol = (((lane & 7) ^ srow) << 3);       // T2: source pre-swizzle
    const int wm = wid >> 1, wn = wid & 1;
    const int fr = lane & 15, fq = lane >> 4;
    const int x7 = fr & 7;
    f32x4 acc[MF][4];
    #pragma unroll
    for (int i = 0; i < MF; ++i)
        #pragma unroll
        for (int j = 0; j < 4; ++j) acc[i][j] = f32x4{0.f, 0.f, 0.f, 0.f};
    const int nkt = K >> 6;
    for (int kt = 0; kt < nkt; ++kt) {
        const int k0 = kt << 6;
        if (kt) __syncthreads();                        // previous compute done reading
        #pragma unroll
        for (int i = 0; i < TM / 32; ++i) {
            int rb = wid * (TM / 4) + i * 8;
            gload16(Az + (size_t)(m0 + rb + srow) * lda + k0 + scol, &As[rb * 64]);
        }
        #pragma unroll
        for (int i = 0; i < 4; ++i) {
            int rb = wid * 32 + i * 8;
            gload16(Bz + (size_t)(n0 + rb + srow) * ldb + k0 + scol, &Bs[rb * 64]);
        }
        __syncthreads();                                // staging complete (vmcnt drain)
        #pragma unroll
        for (int ks = 0; ks < 2; ++ks) {
            const int ck = (((ks * 4 + fq) ^ x7) << 3); // T2: read swizzle
            bf16x8 af[MF], bfr[4];
            #pragma unroll
            for (int mf = 0; mf < MF; ++mf)
                af[mf] = *(const bf16x8*)&As[(wm * (TM / 2) + mf * 16 + fr) * 64 + ck];
            #pragma unroll
            for (int nf = 0; nf < 4; ++nf)
                bfr[nf] = *(const bf16x8*)&Bs[(wn * 64 + nf * 16 + fr) * 64 + ck];
            #pragma unroll
            for (int mf = 0; mf < MF; ++mf)
                #pragma unroll
                for (int nf = 0; nf < 4; ++nf)
                    acc[mf][nf] = __builtin_amdgcn_mfma_f32_16x16x32_bf16(af[mf], bfr[nf], acc[mf][nf], 0, 0, 0);
        }
    }

    if constexpr (TM == 128) {
        if (mode == 1) {
            const int region = n0 / 768;
            const int ncol = n0 - region * 768;
            const int b = m0 >> 10, s0 = m0 & 1023;
            const bool transposed = (region == 1 || region == 2 || region == 5);
            if (!transposed) {
                // regions 0 (qf, elu+1), 3 (qo), 4 (ko): row-major into proj
                #pragma unroll
                for (int mf = 0; mf < 4; ++mf) {
                    #pragma unroll
                    for (int j = 0; j < 4; ++j) {
                        int m = m0 + wm * 64 + mf * 16 + fq * 4 + j;
                        #pragma unroll
                        for (int nf = 0; nf < 4; ++nf) {
                            int n = n0 + wn * 64 + nf * 16 + fr;
                            float t = acc[mf][nf][j] + bias[n];
                            if (region == 0) t = (t > 0.f) ? t + 1.f : expf(t);
                            wsb[O_PROJ + (size_t)m * 4608 + n] = f2bf(t);
                        }
                    }
                }
            } else {
                // regions 1 (kf, elu+1), 2 (vl), 5 (vo): transpose via LDS -> [d][s]
                __syncthreads();
                #pragma unroll
                for (int mf = 0; mf < 4; ++mf) {
                    #pragma unroll
                    for (int nf = 0; nf < 4; ++nf) {
                        int d_l = wn * 64 + nf * 16 + fr;
                        float bs = bias[n0 + d_l];
                        #pragma unroll
                        for (int j = 0; j < 4; ++j) {
                            int s_l = wm * 64 + mf * 16 + fq * 4 + j;
                            float t = acc[mf][nf][j] + bs;
                            if (region == 1) t = (t > 0.f) ? t + 1.f : expf(t);
                            lds[d_l * 136 + s_l] = f2bf(t);
                        }
                    }
                }
                __syncthreads();
                size_t dstT = (region == 1) ? O_KFT : (region == 2) ? O_VLT : O_VOT;
                #pragma unroll
                for (int dd = 0; dd < 8; ++dd) {
                    int d_l = wid * 32 + dd * 4 + (lane >> 4);
                    int sc8 = (lane & 15) * 8;
                    u16x8 v = *(const u16x8*)&lds[d_l * 136 + sc8];
                    *(u16x8*)&wsb[dstT + (size_t)(b * 768 + ncol + d_l) * 1024 + s0 + sc8] = v;
                }
            }
            return;
        }
    }

    float* cfz = Cf ? Cf + (size_t)z * bCf : nullptr;
    ushort* cbz = Cb ? Cb + (size_t)z * bCb : nullptr;
    #pragma unroll
    for (int mf = 0; mf < MF; ++mf) {
        #pragma unroll
        for (int j = 0; j < 4; ++j) {
            int m = m0 + wm * (TM / 2) + mf * 16 + fq * 4 + j;
            float rd = rowdiv ? 1.f / (rowdiv[(size_t)z * M + m] + 1e-6f) : 1.f;
            #pragma unroll
            for (int nf = 0; nf < 4; ++nf) {
                int n = n0 + wn * 64 + nf * 16 + fr;
                float v = acc[mf][nf][j];
                if (bias) v += bias[n];
                v *= rd;
                if (act == 1) v = (v > 0.f) ? v + 1.f : expf(v);
                else if (act == 2) v = fmaxf(v, 0.f);
                else if (act == 3) v = 1.f / (1.f + expf(-v));
                if (mode == 2) {
                    float lin = bf2f(wsb[O_GATEIN + (size_t)m * 2304 + n]);
                    float win = bf2f(wsb[O_GATEIN + (size_t)m * 2304 + 768 + n]);
                    v = v * lin + (1.f - v) * win;
                }
                if (addsrc) v += addsrc[(size_t)m * ldcf + n];
                if (cfz) cfz[(size_t)m * ldcf + n] = v;
                if (cbz) cbz[(size_t)m * ldcb + n] = f2bf(v);
            }
        }
    }
}

// ---------------- kfsum: wave per row of kfT ----------------
__global__ __launch_bounds__(256) void kfsum_kernel(const ushort* __restrict__ wsb,
                                                    float* __restrict__ kfsum) {
    int row = blockIdx.x * 4 + (threadIdx.x >> 6);   // 1536 rows
    int lane = threadIdx.x & 63;
    const ushort* p = wsb + O_KFT + (size_t)row * 1024 + lane * 16;
    float s = 0.f;
    #pragma unroll
    for (int r = 0; r < 2; ++r) {
        u16x8 v = *(const u16x8*)&p[r * 8];
        #pragma unroll
        for (int j = 0; j < 8; ++j) s += bf2f(v[j]);
    }
    #pragma unroll
    for (int o = 32; o > 0; o >>= 1) s += __shfl_xor(s, o);
    if (lane == 0) kfsum[row] = s;
}

// ---------------- normalizer[b,s] = qf . kfsum[b] ----------------
__global__ __launch_bounds__(256) void norm_kernel(const ushort* __restrict__ wsb,
                                                   const float* __restrict__ kfsum,
                                                   float* __restrict__ nrm) {
    int row = blockIdx.x;
    int b = row >> 10;
    const ushort* q = wsb + O_PROJ + (size_t)row * 4608;
    const float* ks = kfsum + b * 768;
    int tid = threadIdx.x;
    float s = 0.f;
    #pragma unroll
    for (int r = 0; r < 3; ++r) {
        int i = tid + r * 256;
        s += bf2f(q[i]) * ks[i];
    }
    #pragma unroll
    for (int o = 32; o > 0; o >>= 1) s += __shfl_down(s, o);
    __shared__ float wsum[4];
    int wid = tid >> 6, lane = tid & 63;
    if (lane == 0) wsum[wid] = s;
    __syncthreads();
    if (tid == 0) nrm[row] = wsum[0] + wsum[1] + wsum[2] + wsum[3];
}

// ---------------- MFMA windowed attention ----------------
// block = (qtile 64, h, b); 4 waves; wave owns 16 q rows.
// Q/K read strided from proj (each head-row = one 128B cache line); V from vot.
__global__ __launch_bounds__(256) void attn_mfma(ushort* __restrict__ wsb) {
    __shared__ __align__(16) ushort Ps[4 * 2048];
    int wq = threadIdx.x >> 6, lane = threadIdx.x & 63;
    int fq = lane >> 4, fr = lane & 15;
    int q0 = blockIdx.x * 64;
    int h = blockIdx.y, b = blockIdx.z;
    const ushort* Pb = wsb + O_PROJ + (size_t)(b * SS) * 4608;
    const ushort* Vb = wsb + O_VOT + (size_t)(b * 768 + h * 64) * 1024;
    const int qoff = 2304 + h * 64, koff = 3072 + h * 64;

    int qrow = q0 + wq * 16 + fr;
    bf16x8 aq0 = *(const bf16x8*)&Pb[(size_t)qrow * 4608 + qoff + fq * 8];
    bf16x8 aq1 = *(const bf16x8*)&Pb[(size_t)qrow * 4608 + qoff + 32 + fq * 8];

    f32x4 sc[8];
    #pragma unroll
    for (int nf = 0; nf < 8; ++nf) sc[nf] = f32x4{0.f, 0.f, 0.f, 0.f};
    #pragma unroll
    for (int nf = 0; nf < 8; ++nf) {
        int kr = q0 - 32 + nf * 16 + fr;
        int kc = kr < 0 ? 0 : (kr > 1023 ? 1023 : kr);
        bf16x8 bk0 = *(const bf16x8*)&Pb[(size_t)kc * 4608 + koff + fq * 8];
        bf16x8 bk1 = *(const bf16x8*)&Pb[(size_t)kc * 4608 + koff + 32 + fq * 8];
        sc[nf] = __builtin_amdgcn_mfma_f32_16x16x32_bf16(aq0, bk0, sc[nf], 0, 0, 0);
        sc[nf] = __builtin_amdgcn_mfma_f32_16x16x32_bf16(aq1, bk1, sc[nf], 0, 0, 0);
    }

    float p[8][4];
    float inv[4];
    #pragma unroll
    for (int j = 0; j < 4; ++j) {
        int qt = wq * 16 + fq * 4 + j;
        float sv[8];
        float mx = -1e30f;
        #pragma unroll
        for (int nf = 0; nf < 8; ++nf) {
            int c = nf * 16 + fr;
            int kg = q0 - 32 + c;
            bool val = (c >= qt) && (c <= qt + 64) && (kg >= 0) && (kg < SS);
            float t = sc[nf][j] * 0.125f;
            sv[nf] = val ? t : -1e30f;
            mx = fmaxf(mx, sv[nf]);
        }
        mx = fmaxf(mx, __shfl_xor(mx, 1));
        mx = fmaxf(mx, __shfl_xor(mx, 2));
        mx = fmaxf(mx, __shfl_xor(mx, 4));
        mx = fmaxf(mx, __shfl_xor(mx, 8));
        float dn = 0.f;
        #pragma unroll
        for (int nf = 0; nf < 8; ++nf) {
            float e = expf(sv[nf] - mx);
            p[nf][j] = e;
            dn += e;
        }
        dn += __shfl_xor(dn, 1);
        dn += __shfl_xor(dn, 2);
        dn += __shfl_xor(dn, 4);
        dn += __shfl_xor(dn, 8);
        inv[j] = 1.f / dn;
    }

    #pragma unroll
    for (int nf = 0; nf < 8; ++nf) {
        int chunk = nf * 2 + (fr >> 3);
        #pragma unroll
        for (int j = 0; j < 4; ++j) {
            int r = fq * 4 + j;
            Ps[wq * 2048 + r * 128 + ((chunk ^ r) * 8) + (fr & 7)] = f2bf(p[nf][j] * inv[j]);
        }
    }
    __syncthreads();

    f32x4 oa[4];
    #pragma unroll
    for (int nf = 0; nf < 4; ++nf) oa[nf] = f32x4{0.f, 0.f, 0.f, 0.f};
    #pragma unroll
    for (int ks = 0; ks < 4; ++ks) {
        bf16x8 pa = *(const bf16x8*)&Ps[wq * 2048 + fr * 128 + (((ks * 4 + fq) ^ fr) * 8)];
        #pragma unroll
        for (int nf = 0; nf < 4; ++nf) {
            int dr = nf * 16 + fr;
            const ushort* vp = Vb + (ptrdiff_t)dr * 1024 + (q0 - 32 + ks * 32 + fq * 8);
            bf16x8 bv = *(const bf16x8*)vp;
            oa[nf] = __builtin_amdgcn_mfma_f32_16x16x32_bf16(pa, bv, oa[nf], 0, 0, 0);
        }
    }

    #pragma unroll
    for (int nf = 0; nf < 4; ++nf) {
        int d = nf * 16 + fr;
        #pragma unroll
        for (int j = 0; j < 4; ++j) {
            int q = q0 + wq * 16 + fq * 4 + j;
            wsb[O_GATEIN + (size_t)(b * SS + q) * 2304 + 768 + h * 64 + d] = f2bf(oa[nf][j]);
        }
    }
}

extern "C" void kernel_launch(void* const* d_in, const int* in_sizes, int n_in,
                              void* d_out, int out_size, void* d_ws, size_t ws_size,
                              hipStream_t stream) {
    const float* x      = (const float*)d_in[0];
    const float* W_q    = (const float*)d_in[1];
    const float* b_q    = (const float*)d_in[2];
    const float* W_k    = (const float*)d_in[3];
    const float* b_k    = (const float*)d_in[4];
    const float* W_v    = (const float*)d_in[5];
    const float* b_v    = (const float*)d_in[6];
    const float* W_ql   = (const float*)d_in[7];
    const float* b_ql   = (const float*)d_in[8];
    const float* W_kl   = (const float*)d_in[9];
    const float* b_kl   = (const float*)d_in[10];
    const float* W_vl   = (const float*)d_in[11];
    const float* b_vl   = (const float*)d_in[12];
    const float* W_out  = (const float*)d_in[13];
    const float* b_out  = (const float*)d_in[14];
    const float* W_g1   = (const float*)d_in[15];
    const float* b_g1   = (const float*)d_in[16];
    const float* W_g2   = (const float*)d_in[17];
    const float* b_g2   = (const float*)d_in[18];
    const float* gamma1 = (const float*)d_in[19];
    const float* beta1  = (const float*)d_in[20];

    ushort* wsb = (ushort*)d_ws;
    float* f32a = (float*)(wsb + O_F32);
    float* bias_cat = f32a;            // 4608
    float* kfsum    = f32a + 4608;     // 1536
    float* nrm      = kfsum + 1536;    // 2048

    const long long W2 = (long long)768 * 768;

    // 1. weight transposes (one dispatch) + bias concat
    TrArgs ta;
    const float* wsrc[6] = {W_q, W_k, W_v, W_ql, W_kl, W_vl};
    for (int i = 0; i < 6; ++i) { ta.src[i] = wsrc[i]; ta.dstOff[i] = O_WPROJT + i * W2; ta.ldo[i] = 768; }
    for (int i = 0; i < 3; ++i) { ta.src[6 + i] = W_g1 + (size_t)i * 768 * 768; ta.dstOff[6 + i] = O_WG1T + i * 768; ta.ldo[6 + i] = 2304; }
    ta.src[9] = W_g2;  ta.dstOff[9] = O_WG2T;  ta.ldo[9] = 768;
    ta.src[10] = W_out; ta.dstOff[10] = O_WOUTT; ta.ldo[10] = 768;
    tr_all<<<dim3(24, 24, 11), 256, 0, stream>>>(ta, wsb);
    bias_cat_kernel<<<dim3(18), 256, 0, stream>>>(b_q, b_k, b_v, b_ql, b_kl, b_vl, bias_cat);

    // 2. LayerNorm -> gate_in slice 2
    ln_kernel<<<dim3(2048), 256, 0, stream>>>(x, gamma1, beta1, wsb);

    // 3. fused 6-way projection (mode 1)
    gemm_bf16<128><<<dim3(36, 16, 1), 256, 0, stream>>>(
        wsb + O_GATEIN + 1536, wsb + O_WPROJT, wsb, nullptr, nullptr, bias_cat, nullptr, nullptr,
        2048, 4608, 768, 2304, 768, 0, 0, 0, 0, 0, 0, 0, 1);

    // 4. kfsum + normalizer
    kfsum_kernel<<<dim3(384), 256, 0, stream>>>(wsb, kfsum);
    norm_kernel<<<dim3(2048), 256, 0, stream>>>(wsb, kfsum, nrm);

    // 5. kvT[b][e][d] = sum_s vl[s,e] kf[s,d]
    gemm_bf16<64><<<dim3(6, 12, 2), 256, 0, stream>>>(
        wsb + O_VLT, wsb + O_KFT, wsb, nullptr, wsb + O_KVT, nullptr, nullptr, nullptr,
        768, 768, 1024, 1024, 1024, 0, 768,
        (long long)768 * 1024, (long long)768 * 1024, 0, W2, 0, 0);

    // 6. lin = (qf @ kvT^T)/nrm -> gate_in slice 0   (qf = proj region 0)
    gemm_bf16<64><<<dim3(6, 16, 2), 256, 0, stream>>>(
        wsb + O_PROJ, wsb + O_KVT, wsb, nullptr, wsb + O_GATEIN, nullptr, nrm, nullptr,
        1024, 768, 768, 4608, 768, 0, 2304,
        (long long)1024 * 4608, W2, 0, (long long)1024 * 2304, 0, 0);

    // 7. windowed attention -> gate_in slice 1
    attn_mfma<<<dim3(16, 12, 2), 256, 0, stream>>>(wsb);

    // 8. h1 = relu(gate_in @ Wg1T^T + b_g1)
    gemm_bf16<64><<<dim3(6, 32, 1), 256, 0, stream>>>(
        wsb + O_GATEIN, wsb + O_WG1T, wsb, nullptr, wsb + O_H1, b_g1, nullptr, nullptr,
        2048, 768, 2304, 2304, 2304, 0, 768, 0, 0, 0, 0, 2, 0);

    // 9. gate = sigmoid(h1 @ Wg2T^T + b_g2); fused = g*lin + (1-g)*win  (mode 2)
    gemm_bf16<64><<<dim3(6, 32, 1), 256, 0, stream>>>(
        wsb + O_H1, wsb + O_WG2T, wsb, nullptr, wsb + O_FUSED, b_g2, nullptr, nullptr,
        2048, 768, 768, 768, 768, 0, 768, 0, 0, 0, 0, 3, 2);

    // 10. out = fused @ WoutT^T + b_out + x
    gemm_bf16<64><<<dim3(6, 32, 1), 256, 0, stream>>>(
        wsb + O_FUSED, wsb + O_WOUTT, wsb, (float*)d_out, nullptr, b_out, nullptr, x,
        2048, 768, 768, 768, 768, 768, 0, 0, 0, (long long)0, 0, 0, 0);
}

// Round 5
// 180.170 us; speedup vs baseline: 8.2268x; 1.0647x over previous
//
#include <hip/hip_runtime.h>
#include <math.h>

#define DD 768
#define SS 1024
#define BB 2
#define HH 12
#define DH 64

typedef __attribute__((ext_vector_type(8))) short bf16x8;
typedef __attribute__((ext_vector_type(8))) unsigned short u16x8;
typedef __attribute__((ext_vector_type(4))) float f32x4;

// ---- workspace layout (ushort units) ----
constexpr size_t O_GATEIN = 0;                                   // [2048][2304] bf16
constexpr size_t O_WPROJT = O_GATEIN + (size_t)2048 * 2304;      // [4608][768]
constexpr size_t O_WG1T   = O_WPROJT + (size_t)4608 * 768;       // [768][2304]
constexpr size_t O_WG2T   = O_WG1T + (size_t)768 * 2304;         // [768][768]
constexpr size_t O_WOUTT  = O_WG2T + (size_t)768 * 768;          // [768][768]
constexpr size_t O_PROJ   = O_WOUTT + (size_t)768 * 768;         // [2048][4608] (regions 0,3,4 used)
constexpr size_t O_KFT    = O_PROJ + (size_t)2048 * 4608;        // [2][768][1024]
constexpr size_t O_VLT    = O_KFT + (size_t)2 * 768 * 1024;      // [2][768][1024]
constexpr size_t O_VOT    = O_VLT + (size_t)2 * 768 * 1024;      // [2][12][64][1024]
constexpr size_t O_KVT    = O_VOT + (size_t)2 * 768 * 1024;      // [2][768][768]
constexpr size_t O_H1     = O_KVT + (size_t)2 * 768 * 768;       // [2048][768]
constexpr size_t O_FUSED  = O_H1 + (size_t)2048 * 768;           // [2048][768]
constexpr size_t O_F32    = O_FUSED + (size_t)2048 * 768;        // f32 area

__device__ inline unsigned short f2bf(float f) {
    unsigned int u = __builtin_bit_cast(unsigned int, f);
    unsigned int r = (u + 0x7fffu + ((u >> 16) & 1u)) >> 16;
    return (unsigned short)r;
}
__device__ inline float bf2f(unsigned short h) {
    unsigned int u = ((unsigned int)h) << 16;
    return __builtin_bit_cast(float, u);
}
__device__ inline void gload16(const ushort* g, ushort* l) {
    __builtin_amdgcn_global_load_lds((const __attribute__((address_space(1))) void*)g,
                                     (__attribute__((address_space(3))) void*)l, 16, 0, 0);
}

// ---------------- LayerNorm -> gate_in slice 2 (bf16) ----------------
__global__ __launch_bounds__(256) void ln_kernel(const float* __restrict__ x,
                                                 const float* __restrict__ gamma,
                                                 const float* __restrict__ beta,
                                                 ushort* __restrict__ wsb) {
    int row = blockIdx.x;
    const float* xr = x + (size_t)row * DD;
    ushort* outr = wsb + O_GATEIN + (size_t)row * 2304 + 1536;
    int tid = threadIdx.x;
    float v[3];
    float s = 0.f, s2 = 0.f;
    #pragma unroll
    for (int r = 0; r < 3; ++r) {
        v[r] = xr[tid + r * 256];
        s += v[r];
        s2 += v[r] * v[r];
    }
    #pragma unroll
    for (int o = 32; o > 0; o >>= 1) {
        s  += __shfl_down(s, o);
        s2 += __shfl_down(s2, o);
    }
    __shared__ float ws1[4], ws2[4];
    int wid = tid >> 6, lane = tid & 63;
    if (lane == 0) { ws1[wid] = s; ws2[wid] = s2; }
    __syncthreads();
    __shared__ float mstat[2];
    if (tid == 0) {
        float a = 0.f, b2 = 0.f;
        #pragma unroll
        for (int i = 0; i < 4; ++i) { a += ws1[i]; b2 += ws2[i]; }
        float mean = a / (float)DD;
        float var = b2 / (float)DD - mean * mean;
        mstat[0] = mean;
        mstat[1] = rsqrtf(var + 1e-5f);
    }
    __syncthreads();
    float mean = mstat[0], rstd = mstat[1];
    #pragma unroll
    for (int r = 0; r < 3; ++r) {
        int i = tid + r * 256;
        outr[i] = f2bf((v[r] - mean) * rstd * gamma[i] + beta[i]);
    }
}

// ---------------- all weight transposes in one dispatch ----------------
struct TrArgs {
    const float* src[11];
    unsigned long long dstOff[11];
    int ldo[11];
};
__global__ __launch_bounds__(256) void tr_all(TrArgs a, ushort* __restrict__ wsb) {
    __shared__ float t[32][33];
    int z = blockIdx.z;
    const float* ip = a.src[z];
    ushort* op = wsb + a.dstOff[z];
    int ldo = a.ldo[z];
    int r0 = blockIdx.y * 32, c0 = blockIdx.x * 32;
    int tx = threadIdx.x & 31, ty = threadIdx.x >> 5;
    #pragma unroll
    for (int i = 0; i < 32; i += 8) t[ty + i][tx] = ip[(size_t)(r0 + ty + i) * 768 + c0 + tx];
    __syncthreads();
    #pragma unroll
    for (int i = 0; i < 32; i += 8) op[(size_t)(c0 + ty + i) * ldo + r0 + tx] = f2bf(t[tx][ty + i]);
}

__global__ void bias_cat_kernel(const float* b0, const float* b1, const float* b2,
                                const float* b3, const float* b4, const float* b5,
                                float* __restrict__ out) {
    int i = blockIdx.x * 256 + threadIdx.x;
    if (i >= 4608) return;
    const float* ps[6] = {b0, b1, b2, b3, b4, b5};
    out[i] = ps[i / 768][i % 768];
}

// ---------------- MFMA bf16 GEMM ----------------
// T3-minimum 2-phase: double-buffered LDS, stage(next) issued BEFORE compute(cur),
// ONE barrier per K-step (compiler's vmcnt(0) at barrier drains the in-flight stage).
// T2 swizzle: staging source col XOR'd with row&7; fragment reads XOR back.
// mode 0: plain epilogue; mode 1: fused projection scatter; mode 2: gate2+fuse.
template<int TM>
__global__ __launch_bounds__(256) void gemm_bf16(
    const ushort* __restrict__ A, const ushort* __restrict__ B,
    ushort* __restrict__ wsb,
    float* __restrict__ Cf, ushort* __restrict__ Cb,
    const float* __restrict__ bias, const float* __restrict__ rowdiv,
    const float* __restrict__ addsrc,
    int M, int N, int K, int lda, int ldb, int ldcf, int ldcb,
    long long bA, long long bB, long long bCf, long long bCb,
    int act, int mode) {
    constexpr int MF = TM / 32;
    constexpr int ASZ = TM * 64;
    constexpr int BSZ = 128 * 64;
    __shared__ __align__(16) ushort lds[2 * ASZ + 2 * BSZ];
    const int tid = threadIdx.x, wid = tid >> 6, lane = tid & 63;
    const int m0 = blockIdx.y * TM, n0 = blockIdx.x * 128, z = blockIdx.z;
    const ushort* Az = A + (size_t)z * bA;
    const ushort* Bz = B + (size_t)z * bB;
    const int srow = lane >> 3;
    const int scol = (((lane & 7) ^ srow) << 3);       // T2: source pre-swizzle
    const int wm = wid >> 1, wn = wid & 1;
    const int fr = lane & 15, fq = lane >> 4;
    const int x7 = fr & 7;
    f32x4 acc[MF][4];
    #pragma unroll
    for (int i = 0; i < MF; ++i)
        #pragma unroll
        for (int j = 0; j < 4; ++j) acc[i][j] = f32x4{0.f, 0.f, 0.f, 0.f};
    const int nkt = K >> 6;

    // prologue: stage tile 0 into buffer 0
    #pragma unroll
    for (int i = 0; i < TM / 32; ++i) {
        int rb = wid * (TM / 4) + i * 8;
        gload16(Az + (size_t)(m0 + rb + srow) * lda + scol, &lds[rb * 64]);
    }
    #pragma unroll
    for (int i = 0; i < 4; ++i) {
        int rb = wid * 32 + i * 8;
        gload16(Bz + (size_t)(n0 + rb + srow) * ldb + scol, &lds[2 * ASZ + rb * 64]);
    }
    __syncthreads();

    int cur = 0;
    for (int kt = 0; kt < nkt; ++kt) {
        // issue next tile's loads FIRST (in flight during compute below)
        if (kt + 1 < nkt) {
            const int k0 = (kt + 1) << 6;
            const int nxt = cur ^ 1;
            #pragma unroll
            for (int i = 0; i < TM / 32; ++i) {
                int rb = wid * (TM / 4) + i * 8;
                gload16(Az + (size_t)(m0 + rb + srow) * lda + k0 + scol, &lds[nxt * ASZ + rb * 64]);
            }
            #pragma unroll
            for (int i = 0; i < 4; ++i) {
                int rb = wid * 32 + i * 8;
                gload16(Bz + (size_t)(n0 + rb + srow) * ldb + k0 + scol, &lds[2 * ASZ + nxt * BSZ + rb * 64]);
            }
        }
        // compute current buffer
        const ushort* As = &lds[cur * ASZ];
        const ushort* Bs = &lds[2 * ASZ + cur * BSZ];
        #pragma unroll
        for (int ks = 0; ks < 2; ++ks) {
            const int ck = (((ks * 4 + fq) ^ x7) << 3); // T2: read swizzle
            bf16x8 af[MF], bfr[4];
            #pragma unroll
            for (int mf = 0; mf < MF; ++mf)
                af[mf] = *(const bf16x8*)&As[(wm * (TM / 2) + mf * 16 + fr) * 64 + ck];
            #pragma unroll
            for (int nf = 0; nf < 4; ++nf)
                bfr[nf] = *(const bf16x8*)&Bs[(wn * 64 + nf * 16 + fr) * 64 + ck];
            #pragma unroll
            for (int mf = 0; mf < MF; ++mf)
                #pragma unroll
                for (int nf = 0; nf < 4; ++nf)
                    acc[mf][nf] = __builtin_amdgcn_mfma_f32_16x16x32_bf16(af[mf], bfr[nf], acc[mf][nf], 0, 0, 0);
        }
        __syncthreads();   // drains in-flight stage (vmcnt 0) + read-done for next overwrite
        cur ^= 1;
    }

    if constexpr (TM == 128) {
        if (mode == 1) {
            const int region = n0 / 768;
            const int ncol = n0 - region * 768;
            const int b = m0 >> 10, s0 = m0 & 1023;
            const bool transposed = (region == 1 || region == 2 || region == 5);
            if (!transposed) {
                // regions 0 (qf, elu+1), 3 (qo), 4 (ko): row-major into proj
                #pragma unroll
                for (int mf = 0; mf < 4; ++mf) {
                    #pragma unroll
                    for (int j = 0; j < 4; ++j) {
                        int m = m0 + wm * 64 + mf * 16 + fq * 4 + j;
                        #pragma unroll
                        for (int nf = 0; nf < 4; ++nf) {
                            int n = n0 + wn * 64 + nf * 16 + fr;
                            float t = acc[mf][nf][j] + bias[n];
                            if (region == 0) t = (t > 0.f) ? t + 1.f : expf(t);
                            wsb[O_PROJ + (size_t)m * 4608 + n] = f2bf(t);
                        }
                    }
                }
            } else {
                // regions 1 (kf, elu+1), 2 (vl), 5 (vo): transpose via LDS -> [d][s]
                #pragma unroll
                for (int mf = 0; mf < 4; ++mf) {
                    #pragma unroll
                    for (int nf = 0; nf < 4; ++nf) {
                        int d_l = wn * 64 + nf * 16 + fr;
                        float bs = bias[n0 + d_l];
                        #pragma unroll
                        for (int j = 0; j < 4; ++j) {
                            int s_l = wm * 64 + mf * 16 + fq * 4 + j;
                            float t = acc[mf][nf][j] + bs;
                            if (region == 1) t = (t > 0.f) ? t + 1.f : expf(t);
                            lds[d_l * 136 + s_l] = f2bf(t);
                        }
                    }
                }
                __syncthreads();
                size_t dstT = (region == 1) ? O_KFT : (region == 2) ? O_VLT : O_VOT;
                #pragma unroll
                for (int dd = 0; dd < 8; ++dd) {
                    int d_l = wid * 32 + dd * 4 + (lane >> 4);
                    int sc8 = (lane & 15) * 8;
                    u16x8 v = *(const u16x8*)&lds[d_l * 136 + sc8];
                    *(u16x8*)&wsb[dstT + (size_t)(b * 768 + ncol + d_l) * 1024 + s0 + sc8] = v;
                }
            }
            return;
        }
    }

    float* cfz = Cf ? Cf + (size_t)z * bCf : nullptr;
    ushort* cbz = Cb ? Cb + (size_t)z * bCb : nullptr;
    #pragma unroll
    for (int mf = 0; mf < MF; ++mf) {
        #pragma unroll
        for (int j = 0; j < 4; ++j) {
            int m = m0 + wm * (TM / 2) + mf * 16 + fq * 4 + j;
            float rd = rowdiv ? 1.f / (rowdiv[(size_t)z * M + m] + 1e-6f) : 1.f;
            #pragma unroll
            for (int nf = 0; nf < 4; ++nf) {
                int n = n0 + wn * 64 + nf * 16 + fr;
                float v = acc[mf][nf][j];
                if (bias) v += bias[n];
                v *= rd;
                if (act == 1) v = (v > 0.f) ? v + 1.f : expf(v);
                else if (act == 2) v = fmaxf(v, 0.f);
                else if (act == 3) v = 1.f / (1.f + expf(-v));
                if (mode == 2) {
                    float lin = bf2f(wsb[O_GATEIN + (size_t)m * 2304 + n]);
                    float win = bf2f(wsb[O_GATEIN + (size_t)m * 2304 + 768 + n]);
                    v = v * lin + (1.f - v) * win;
                }
                if (addsrc) v += addsrc[(size_t)m * ldcf + n];
                if (cfz) cfz[(size_t)m * ldcf + n] = v;
                if (cbz) cbz[(size_t)m * ldcb + n] = f2bf(v);
            }
        }
    }
}

// ---------------- kfsum: wave per row of kfT ----------------
__global__ __launch_bounds__(256) void kfsum_kernel(const ushort* __restrict__ wsb,
                                                    float* __restrict__ kfsum) {
    int row = blockIdx.x * 4 + (threadIdx.x >> 6);   // 1536 rows
    int lane = threadIdx.x & 63;
    const ushort* p = wsb + O_KFT + (size_t)row * 1024 + lane * 16;
    float s = 0.f;
    #pragma unroll
    for (int r = 0; r < 2; ++r) {
        u16x8 v = *(const u16x8*)&p[r * 8];
        #pragma unroll
        for (int j = 0; j < 8; ++j) s += bf2f(v[j]);
    }
    #pragma unroll
    for (int o = 32; o > 0; o >>= 1) s += __shfl_xor(s, o);
    if (lane == 0) kfsum[row] = s;
}

// ---------------- normalizer[b,s] = qf . kfsum[b] ----------------
__global__ __launch_bounds__(256) void norm_kernel(const ushort* __restrict__ wsb,
                                                   const float* __restrict__ kfsum,
                                                   float* __restrict__ nrm) {
    int row = blockIdx.x;
    int b = row >> 10;
    const ushort* q = wsb + O_PROJ + (size_t)row * 4608;
    const float* ks = kfsum + b * 768;
    int tid = threadIdx.x;
    float s = 0.f;
    #pragma unroll
    for (int r = 0; r < 3; ++r) {
        int i = tid + r * 256;
        s += bf2f(q[i]) * ks[i];
    }
    #pragma unroll
    for (int o = 32; o > 0; o >>= 1) s += __shfl_down(s, o);
    __shared__ float wsum[4];
    int wid = tid >> 6, lane = tid & 63;
    if (lane == 0) wsum[wid] = s;
    __syncthreads();
    if (tid == 0) nrm[row] = wsum[0] + wsum[1] + wsum[2] + wsum[3];
}

// ---------------- MFMA windowed attention ----------------
// block = (qtile 64, h, b); 4 waves; wave owns 16 q rows.
// Q/K read strided from proj (each head-row = one 128B cache line); V from vot.
__global__ __launch_bounds__(256) void attn_mfma(ushort* __restrict__ wsb) {
    __shared__ __align__(16) ushort Ps[4 * 2048];
    int wq = threadIdx.x >> 6, lane = threadIdx.x & 63;
    int fq = lane >> 4, fr = lane & 15;
    int q0 = blockIdx.x * 64;
    int h = blockIdx.y, b = blockIdx.z;
    const ushort* Pb = wsb + O_PROJ + (size_t)(b * SS) * 4608;
    const ushort* Vb = wsb + O_VOT + (size_t)(b * 768 + h * 64) * 1024;
    const int qoff = 2304 + h * 64, koff = 3072 + h * 64;

    int qrow = q0 + wq * 16 + fr;
    bf16x8 aq0 = *(const bf16x8*)&Pb[(size_t)qrow * 4608 + qoff + fq * 8];
    bf16x8 aq1 = *(const bf16x8*)&Pb[(size_t)qrow * 4608 + qoff + 32 + fq * 8];

    f32x4 sc[8];
    #pragma unroll
    for (int nf = 0; nf < 8; ++nf) sc[nf] = f32x4{0.f, 0.f, 0.f, 0.f};
    #pragma unroll
    for (int nf = 0; nf < 8; ++nf) {
        int kr = q0 - 32 + nf * 16 + fr;
        int kc = kr < 0 ? 0 : (kr > 1023 ? 1023 : kr);
        bf16x8 bk0 = *(const bf16x8*)&Pb[(size_t)kc * 4608 + koff + fq * 8];
        bf16x8 bk1 = *(const bf16x8*)&Pb[(size_t)kc * 4608 + koff + 32 + fq * 8];
        sc[nf] = __builtin_amdgcn_mfma_f32_16x16x32_bf16(aq0, bk0, sc[nf], 0, 0, 0);
        sc[nf] = __builtin_amdgcn_mfma_f32_16x16x32_bf16(aq1, bk1, sc[nf], 0, 0, 0);
    }

    float p[8][4];
    float inv[4];
    #pragma unroll
    for (int j = 0; j < 4; ++j) {
        int qt = wq * 16 + fq * 4 + j;
        float sv[8];
        float mx = -1e30f;
        #pragma unroll
        for (int nf = 0; nf < 8; ++nf) {
            int c = nf * 16 + fr;
            int kg = q0 - 32 + c;
            bool val = (c >= qt) && (c <= qt + 64) && (kg >= 0) && (kg < SS);
            float t = sc[nf][j] * 0.125f;
            sv[nf] = val ? t : -1e30f;
            mx = fmaxf(mx, sv[nf]);
        }
        mx = fmaxf(mx, __shfl_xor(mx, 1));
        mx = fmaxf(mx, __shfl_xor(mx, 2));
        mx = fmaxf(mx, __shfl_xor(mx, 4));
        mx = fmaxf(mx, __shfl_xor(mx, 8));
        float dn = 0.f;
        #pragma unroll
        for (int nf = 0; nf < 8; ++nf) {
            float e = expf(sv[nf] - mx);
            p[nf][j] = e;
            dn += e;
        }
        dn += __shfl_xor(dn, 1);
        dn += __shfl_xor(dn, 2);
        dn += __shfl_xor(dn, 4);
        dn += __shfl_xor(dn, 8);
        inv[j] = 1.f / dn;
    }

    #pragma unroll
    for (int nf = 0; nf < 8; ++nf) {
        int chunk = nf * 2 + (fr >> 3);
        #pragma unroll
        for (int j = 0; j < 4; ++j) {
            int r = fq * 4 + j;
            Ps[wq * 2048 + r * 128 + ((chunk ^ r) * 8) + (fr & 7)] = f2bf(p[nf][j] * inv[j]);
        }
    }
    __syncthreads();

    f32x4 oa[4];
    #pragma unroll
    for (int nf = 0; nf < 4; ++nf) oa[nf] = f32x4{0.f, 0.f, 0.f, 0.f};
    #pragma unroll
    for (int ks = 0; ks < 4; ++ks) {
        bf16x8 pa = *(const bf16x8*)&Ps[wq * 2048 + fr * 128 + (((ks * 4 + fq) ^ fr) * 8)];
        #pragma unroll
        for (int nf = 0; nf < 4; ++nf) {
            int dr = nf * 16 + fr;
            const ushort* vp = Vb + (ptrdiff_t)dr * 1024 + (q0 - 32 + ks * 32 + fq * 8);
            bf16x8 bv = *(const bf16x8*)vp;
            oa[nf] = __builtin_amdgcn_mfma_f32_16x16x32_bf16(pa, bv, oa[nf], 0, 0, 0);
        }
    }

    #pragma unroll
    for (int nf = 0; nf < 4; ++nf) {
        int d = nf * 16 + fr;
        #pragma unroll
        for (int j = 0; j < 4; ++j) {
            int q = q0 + wq * 16 + fq * 4 + j;
            wsb[O_GATEIN + (size_t)(b * SS + q) * 2304 + 768 + h * 64 + d] = f2bf(oa[nf][j]);
        }
    }
}

extern "C" void kernel_launch(void* const* d_in, const int* in_sizes, int n_in,
                              void* d_out, int out_size, void* d_ws, size_t ws_size,
                              hipStream_t stream) {
    const float* x      = (const float*)d_in[0];
    const float* W_q    = (const float*)d_in[1];
    const float* b_q    = (const float*)d_in[2];
    const float* W_k    = (const float*)d_in[3];
    const float* b_k    = (const float*)d_in[4];
    const float* W_v    = (const float*)d_in[5];
    const float* b_v    = (const float*)d_in[6];
    const float* W_ql   = (const float*)d_in[7];
    const float* b_ql   = (const float*)d_in[8];
    const float* W_kl   = (const float*)d_in[9];
    const float* b_kl   = (const float*)d_in[10];
    const float* W_vl   = (const float*)d_in[11];
    const float* b_vl   = (const float*)d_in[12];
    const float* W_out  = (const float*)d_in[13];
    const float* b_out  = (const float*)d_in[14];
    const float* W_g1   = (const float*)d_in[15];
    const float* b_g1   = (const float*)d_in[16];
    const float* W_g2   = (const float*)d_in[17];
    const float* b_g2   = (const float*)d_in[18];
    const float* gamma1 = (const float*)d_in[19];
    const float* beta1  = (const float*)d_in[20];

    ushort* wsb = (ushort*)d_ws;
    float* f32a = (float*)(wsb + O_F32);
    float* bias_cat = f32a;            // 4608
    float* kfsum    = f32a + 4608;     // 1536
    float* nrm      = kfsum + 1536;    // 2048

    const long long W2 = (long long)768 * 768;

    // 1. weight transposes (one dispatch) + bias concat
    TrArgs ta;
    const float* wsrc[6] = {W_q, W_k, W_v, W_ql, W_kl, W_vl};
    for (int i = 0; i < 6; ++i) { ta.src[i] = wsrc[i]; ta.dstOff[i] = O_WPROJT + i * W2; ta.ldo[i] = 768; }
    for (int i = 0; i < 3; ++i) { ta.src[6 + i] = W_g1 + (size_t)i * 768 * 768; ta.dstOff[6 + i] = O_WG1T + i * 768; ta.ldo[6 + i] = 2304; }
    ta.src[9] = W_g2;  ta.dstOff[9] = O_WG2T;  ta.ldo[9] = 768;
    ta.src[10] = W_out; ta.dstOff[10] = O_WOUTT; ta.ldo[10] = 768;
    tr_all<<<dim3(24, 24, 11), 256, 0, stream>>>(ta, wsb);
    bias_cat_kernel<<<dim3(18), 256, 0, stream>>>(b_q, b_k, b_v, b_ql, b_kl, b_vl, bias_cat);

    // 2. LayerNorm -> gate_in slice 2
    ln_kernel<<<dim3(2048), 256, 0, stream>>>(x, gamma1, beta1, wsb);

    // 3. fused 6-way projection (mode 1)
    gemm_bf16<128><<<dim3(36, 16, 1), 256, 0, stream>>>(
        wsb + O_GATEIN + 1536, wsb + O_WPROJT, wsb, nullptr, nullptr, bias_cat, nullptr, nullptr,
        2048, 4608, 768, 2304, 768, 0, 0, 0, 0, 0, 0, 0, 1);

    // 4. kfsum + normalizer
    kfsum_kernel<<<dim3(384), 256, 0, stream>>>(wsb, kfsum);
    norm_kernel<<<dim3(2048), 256, 0, stream>>>(wsb, kfsum, nrm);

    // 5. kvT[b][e][d] = sum_s vl[s,e] kf[s,d]
    gemm_bf16<64><<<dim3(6, 12, 2), 256, 0, stream>>>(
        wsb + O_VLT, wsb + O_KFT, wsb, nullptr, wsb + O_KVT, nullptr, nullptr, nullptr,
        768, 768, 1024, 1024, 1024, 0, 768,
        (long long)768 * 1024, (long long)768 * 1024, 0, W2, 0, 0);

    // 6. lin = (qf @ kvT^T)/nrm -> gate_in slice 0   (qf = proj region 0)
    gemm_bf16<64><<<dim3(6, 16, 2), 256, 0, stream>>>(
        wsb + O_PROJ, wsb + O_KVT, wsb, nullptr, wsb + O_GATEIN, nullptr, nrm, nullptr,
        1024, 768, 768, 4608, 768, 0, 2304,
        (long long)1024 * 4608, W2, 0, (long long)1024 * 2304, 0, 0);

    // 7. windowed attention -> gate_in slice 1
    attn_mfma<<<dim3(16, 12, 2), 256, 0, stream>>>(wsb);

    // 8. h1 = relu(gate_in @ Wg1T^T + b_g1)
    gemm_bf16<64><<<dim3(6, 32, 1), 256, 0, stream>>>(
        wsb + O_GATEIN, wsb + O_WG1T, wsb, nullptr, wsb + O_H1, b_g1, nullptr, nullptr,
        2048, 768, 2304, 2304, 2304, 0, 768, 0, 0, 0, 0, 2, 0);

    // 9. gate = sigmoid(h1 @ Wg2T^T + b_g2); fused = g*lin + (1-g)*win  (mode 2)
    gemm_bf16<64><<<dim3(6, 32, 1), 256, 0, stream>>>(
        wsb + O_H1, wsb + O_WG2T, wsb, nullptr, wsb + O_FUSED, b_g2, nullptr, nullptr,
        2048, 768, 768, 768, 768, 0, 768, 0, 0, 0, 0, 3, 2);

    // 10. out = fused @ WoutT^T + b_out + x
    gemm_bf16<64><<<dim3(6, 32, 1), 256, 0, stream>>>(
        wsb + O_FUSED, wsb + O_WOUTT, wsb, (float*)d_out, nullptr, b_out, nullptr, x,
        2048, 768, 768, 768, 768, 768, 0, 0, 0, (long long)0, 0, 0, 0);
}